// Round 2
// baseline (1872.049 us; speedup 1.0000x reference)
//
#include <hip/hip_runtime.h>
#include <cstdint>

#define B_   2
#define S_   4096
#define DM   1024
#define NH   8
#define HDIM 128
#define NWIN 15

__device__ __forceinline__ float f_lo(unsigned int u){
  union { unsigned int i; float f; } v; v.i = u << 16; return v.f;
}
__device__ __forceinline__ float f_hi(unsigned int u){
  union { unsigned int i; float f; } v; v.i = u & 0xffff0000u; return v.f;
}
__device__ __forceinline__ unsigned short f2bf(float f){
  unsigned int x = __float_as_uint(f);
  x += 0x7fffu + ((x >> 16) & 1u);
  return (unsigned short)(x >> 16);
}

// ---------------------------------------------------------------------------
// Broadcast diffusion: 12 steps of cur[s] += 0.5*(cur[s-st]+cur[s+st]) (circular),
// result = sum of cur after each step, /13. Per (b,d) column fully in LDS.
// 2 channels per block: bufA/bufB ping-pong 2x4096 fp32 = 64KB LDS.
// ---------------------------------------------------------------------------
__global__ __launch_bounds__(256) void k_diffuse(const float* __restrict__ x,
                                                 unsigned short* __restrict__ bc){
  __shared__ float bufA[2][4096];
  __shared__ float bufB[2][4096];
  const int b  = blockIdx.x >> 9;
  const int d0 = (blockIdx.x & 511) * 2;
  const int tid = threadIdx.x;
  float res[32];
#pragma unroll
  for(int k=0;k<32;k++){
    int e = tid + (k<<8); int ch = e>>12; int s = e&4095;
    bufA[ch][s] = x[(size_t)(b*S_+s)*DM + d0 + ch];
    res[k] = 0.f;
  }
  __syncthreads();
#pragma unroll 1
  for(int st=0; st<12; st++){
    const int stride = 1<<st;
    float (*src)[4096] = (st&1) ? bufB : bufA;
    float (*dst)[4096] = (st&1) ? bufA : bufB;
#pragma unroll
    for(int k=0;k<32;k++){
      int e = tid + (k<<8); int ch=e>>12; int s=e&4095;
      float c = src[ch][s] + 0.5f*(src[ch][(s-stride)&4095] + src[ch][(s+stride)&4095]);
      dst[ch][s] = c; res[k] += c;
    }
    __syncthreads();
  }
#pragma unroll
  for(int k=0;k<32;k++){
    int e = tid + (k<<8); int ch=e>>12; int s=e&4095;
    bc[(size_t)(b*S_+s)*DM + d0 + ch] = f2bf(res[k]*(1.0f/13.0f));
  }
}

// ---------------------------------------------------------------------------
// Conv1d(k=4,stride=4) for first 64 output positions -> kv[:, :, 0:64, :] (bf16)
// comp[b,t,o] = cb[o] + sum_{d,k} x[b,4t+k,d]*cw[o,d,k]
// grid 512: (b, t, oc), 256 threads, 1 output channel each (o = oc*256+tid).
// xs LDS layout xs[d*4+k] so compute reads are float4.
// ---------------------------------------------------------------------------
__global__ __launch_bounds__(256) void k_conv(const float* __restrict__ x,
                                              const float* __restrict__ cw,
                                              const float* __restrict__ cb,
                                              unsigned short* __restrict__ kv){
  __shared__ float xs[4096];
  const int b  = blockIdx.x >> 8;
  const int t  = (blockIdx.x >> 2) & 63;
  const int oc = blockIdx.x & 3;
  const int tid = threadIdx.x;
  const float* xp = x + (size_t)(b*S_ + 4*t)*DM;
  for(int i=tid; i<4096; i+=256){
    xs[((i & 1023)<<2) | (i>>10)] = xp[i];
  }
  __syncthreads();
  const int o = oc*256 + tid;
  float acc = cb[o];
  const float* cwo = cw + (size_t)o*4096;
  for(int d=0; d<1024; d+=2){
    float4 w0 = *(const float4*)(cwo + (d<<2));
    float4 w1 = *(const float4*)(cwo + (d<<2) + 4);
    float4 xa = *(const float4*)&xs[d<<2];
    float4 xb = *(const float4*)&xs[(d<<2)+4];
    acc += xa.x*w0.x + xa.y*w0.y + xa.z*w0.z + xa.w*w0.w
         + xb.x*w1.x + xb.y*w1.y + xb.z*w1.z + xb.w*w1.w;
  }
  const int h = o >> 7, hd = o & 127;
  kv[((size_t)(b*NH + h)*128 + t)*HDIM + hd] = f2bf(acc);
}

// gmem broadcast -> kv[:, :, 64:128, :] (bf16)
__global__ __launch_bounds__(256) void k_gmem(const float* __restrict__ g,
                                              unsigned short* __restrict__ kv){
  int i = blockIdx.x*256 + threadIdx.x;   // 131072 total
  int hd = i & 127, gt = (i>>7)&63, h = (i>>13)&7, b = i>>16;
  kv[((size_t)(b*NH + h)*128 + 64 + gt)*HDIM + hd] = f2bf(g[((size_t)(h*64 + gt))*HDIM + hd]);
}

// ---------------------------------------------------------------------------
// Sliding-window attention, flash-style. Block = (b, n, h, qtile of 32 queries).
// KV tiles of 64 keys (8 tiles over the 512-token window), online softmax.
// Thread mapping: qh=tid>>4 owns q rows {2qh,2qh+1}; tl=tid&15.
// Scores: t = tl+16i (i<4). PV: hd = tl*8..tl*8+7. Softmax stats shfl over 16 lanes.
// Outputs raw per-window attention to wso (bf16); combine pass applies tri weights.
// ---------------------------------------------------------------------------
__global__ __launch_bounds__(256) void k_swin(const float* __restrict__ x,
                                              unsigned short* __restrict__ wso){
  __shared__ float Qs[32][132];
  __shared__ float KVs[64][132];
  __shared__ float Ps[32][72];
  const int bid  = blockIdx.x;
  const int qt   = bid & 15;
  const int h    = (bid >> 4) & 7;
  const int rest = bid >> 7;
  const int n    = rest % NWIN;
  const int b    = rest / NWIN;
  const int tid  = threadIdx.x;
  const int qh   = tid >> 4;
  const int tl   = tid & 15;
  const int hd0  = tl * 8;
  const int q0r  = qh * 2;
  const int s0   = n*256 + qt*32;

  for(int i = tid; i < 1024; i += 256){
    int row = i >> 5, c4 = i & 31;
    float4 v = *(const float4*)(x + (size_t)(b*S_ + s0 + row)*DM + h*HDIM + c4*4);
    *(float4*)&Qs[row][c4*4] = v;
  }

  float accA[8], accB[8];
#pragma unroll
  for(int j=0;j<8;j++){ accA[j]=0.f; accB[j]=0.f; }
  float m0 = -1e30f, m1 = -1e30f, l0 = 0.f, l1 = 0.f;

  for(int kt = 0; kt < 8; kt++){
    __syncthreads();
    const int k0 = n*256 + kt*64;
    for(int i = tid; i < 2048; i += 256){
      int row = i >> 5, c4 = i & 31;
      float4 v = *(const float4*)(x + (size_t)(b*S_ + k0 + row)*DM + h*HDIM + c4*4);
      *(float4*)&KVs[row][c4*4] = v;
    }
    __syncthreads();

    float sA[4], sB[4];
#pragma unroll
    for(int i=0;i<4;i++){ sA[i]=0.f; sB[i]=0.f; }
#pragma unroll 4
    for(int d=0; d<128; d+=4){
      float4 qa = *(const float4*)&Qs[q0r][d];
      float4 qb = *(const float4*)&Qs[q0r+1][d];
#pragma unroll
      for(int i=0;i<4;i++){
        float4 kvv = *(const float4*)&KVs[tl + 16*i][d];
        sA[i] += qa.x*kvv.x + qa.y*kvv.y + qa.z*kvv.z + qa.w*kvv.w;
        sB[i] += qb.x*kvv.x + qb.y*kvv.y + qb.z*kvv.z + qb.w*kvv.w;
      }
    }
    const float SC = 0.08838834764831845f;
    float t0 = -1e30f, t1 = -1e30f;
#pragma unroll
    for(int i=0;i<4;i++){
      sA[i] *= SC; sB[i] *= SC;
      t0 = fmaxf(t0, sA[i]); t1 = fmaxf(t1, sB[i]);
    }
#pragma unroll
    for(int off=1; off<16; off<<=1){
      t0 = fmaxf(t0, __shfl_xor(t0, off));
      t1 = fmaxf(t1, __shfl_xor(t1, off));
    }
    float mn0 = fmaxf(m0, t0), mn1 = fmaxf(m1, t1);
    float al0 = __expf(m0 - mn0), al1 = __expf(m1 - mn1);
    float ps0 = 0.f, ps1 = 0.f;
#pragma unroll
    for(int i=0;i<4;i++){
      float p0 = __expf(sA[i] - mn0);
      float p1 = __expf(sB[i] - mn1);
      Ps[q0r][tl + 16*i]   = p0;
      Ps[q0r+1][tl + 16*i] = p1;
      ps0 += p0; ps1 += p1;
    }
#pragma unroll
    for(int off=1; off<16; off<<=1){
      ps0 += __shfl_xor(ps0, off);
      ps1 += __shfl_xor(ps1, off);
    }
    l0 = l0*al0 + ps0; l1 = l1*al1 + ps1;
    m0 = mn0; m1 = mn1;
#pragma unroll
    for(int j=0;j<8;j++){ accA[j]*=al0; accB[j]*=al1; }
    // Ps rows written/read only by this 16-lane group (same wave): no barrier needed.
#pragma unroll 4
    for(int t=0; t<64; t++){
      float p0 = Ps[q0r][t];
      float p1 = Ps[q0r+1][t];
      float4 va = *(const float4*)&KVs[t][hd0];
      float4 vb = *(const float4*)&KVs[t][hd0+4];
      accA[0]+=p0*va.x; accA[1]+=p0*va.y; accA[2]+=p0*va.z; accA[3]+=p0*va.w;
      accA[4]+=p0*vb.x; accA[5]+=p0*vb.y; accA[6]+=p0*vb.z; accA[7]+=p0*vb.w;
      accB[0]+=p1*va.x; accB[1]+=p1*va.y; accB[2]+=p1*va.z; accB[3]+=p1*va.w;
      accB[4]+=p1*vb.x; accB[5]+=p1*vb.y; accB[6]+=p1*vb.z; accB[7]+=p1*vb.w;
    }
  }
  float li0 = 1.0f/l0, li1 = 1.0f/l1;
  size_t ob0 = (size_t)((b*NWIN + n)*512 + qt*32 + q0r)*DM + h*HDIM + hd0;
  size_t ob1 = ob0 + DM;
#pragma unroll
  for(int j=0;j<8;j++){
    wso[ob0 + j] = f2bf(accA[j]*li0);
    wso[ob1 + j] = f2bf(accB[j]*li1);
  }
}

// ---------------------------------------------------------------------------
// Compressed-global attention: same structure, 2 KV tiles of 64 (128 kv tokens),
// KV from bf16 kv buffer, output (bf16) to glob.
// ---------------------------------------------------------------------------
__global__ __launch_bounds__(256) void k_gattn(const float* __restrict__ x,
                                               const unsigned short* __restrict__ kvb,
                                               unsigned short* __restrict__ glob){
  __shared__ float Qs[32][132];
  __shared__ float KVs[64][132];
  __shared__ float Ps[32][72];
  const int bid = blockIdx.x;
  const int qt  = bid & 127;
  const int h   = (bid >> 7) & 7;
  const int b   = bid >> 10;
  const int tid = threadIdx.x;
  const int qh  = tid >> 4;
  const int tl  = tid & 15;
  const int hd0 = tl * 8;
  const int q0r = qh * 2;
  const int s0  = qt*32;

  for(int i = tid; i < 1024; i += 256){
    int row = i >> 5, c4 = i & 31;
    float4 v = *(const float4*)(x + (size_t)(b*S_ + s0 + row)*DM + h*HDIM + c4*4);
    *(float4*)&Qs[row][c4*4] = v;
  }

  float accA[8], accB[8];
#pragma unroll
  for(int j=0;j<8;j++){ accA[j]=0.f; accB[j]=0.f; }
  float m0 = -1e30f, m1 = -1e30f, l0 = 0.f, l1 = 0.f;

  for(int kt = 0; kt < 2; kt++){
    __syncthreads();
    for(int i = tid; i < 4096; i += 256){
      int row = i >> 6, colp = i & 63;
      unsigned int u = *(const unsigned int*)(kvb + (size_t)((b*NH + h)*128 + kt*64 + row)*HDIM + colp*2);
      KVs[row][colp*2]     = f_lo(u);
      KVs[row][colp*2 + 1] = f_hi(u);
    }
    __syncthreads();

    float sA[4], sB[4];
#pragma unroll
    for(int i=0;i<4;i++){ sA[i]=0.f; sB[i]=0.f; }
#pragma unroll 4
    for(int d=0; d<128; d+=4){
      float4 qa = *(const float4*)&Qs[q0r][d];
      float4 qb = *(const float4*)&Qs[q0r+1][d];
#pragma unroll
      for(int i=0;i<4;i++){
        float4 kvv = *(const float4*)&KVs[tl + 16*i][d];
        sA[i] += qa.x*kvv.x + qa.y*kvv.y + qa.z*kvv.z + qa.w*kvv.w;
        sB[i] += qb.x*kvv.x + qb.y*kvv.y + qb.z*kvv.z + qb.w*kvv.w;
      }
    }
    const float SC = 0.08838834764831845f;
    float t0 = -1e30f, t1 = -1e30f;
#pragma unroll
    for(int i=0;i<4;i++){
      sA[i] *= SC; sB[i] *= SC;
      t0 = fmaxf(t0, sA[i]); t1 = fmaxf(t1, sB[i]);
    }
#pragma unroll
    for(int off=1; off<16; off<<=1){
      t0 = fmaxf(t0, __shfl_xor(t0, off));
      t1 = fmaxf(t1, __shfl_xor(t1, off));
    }
    float mn0 = fmaxf(m0, t0), mn1 = fmaxf(m1, t1);
    float al0 = __expf(m0 - mn0), al1 = __expf(m1 - mn1);
    float ps0 = 0.f, ps1 = 0.f;
#pragma unroll
    for(int i=0;i<4;i++){
      float p0 = __expf(sA[i] - mn0);
      float p1 = __expf(sB[i] - mn1);
      Ps[q0r][tl + 16*i]   = p0;
      Ps[q0r+1][tl + 16*i] = p1;
      ps0 += p0; ps1 += p1;
    }
#pragma unroll
    for(int off=1; off<16; off<<=1){
      ps0 += __shfl_xor(ps0, off);
      ps1 += __shfl_xor(ps1, off);
    }
    l0 = l0*al0 + ps0; l1 = l1*al1 + ps1;
    m0 = mn0; m1 = mn1;
#pragma unroll
    for(int j=0;j<8;j++){ accA[j]*=al0; accB[j]*=al1; }
#pragma unroll 4
    for(int t=0; t<64; t++){
      float p0 = Ps[q0r][t];
      float p1 = Ps[q0r+1][t];
      float4 va = *(const float4*)&KVs[t][hd0];
      float4 vb = *(const float4*)&KVs[t][hd0+4];
      accA[0]+=p0*va.x; accA[1]+=p0*va.y; accA[2]+=p0*va.z; accA[3]+=p0*va.w;
      accA[4]+=p0*vb.x; accA[5]+=p0*vb.y; accA[6]+=p0*vb.z; accA[7]+=p0*vb.w;
      accB[0]+=p1*va.x; accB[1]+=p1*va.y; accB[2]+=p1*va.z; accB[3]+=p1*va.w;
      accB[4]+=p1*vb.x; accB[5]+=p1*vb.y; accB[6]+=p1*vb.z; accB[7]+=p1*vb.w;
    }
  }
  float li0 = 1.0f/l0, li1 = 1.0f/l1;
  size_t ob0 = (size_t)(b*S_ + s0 + q0r)*DM + h*HDIM + hd0;
  size_t ob1 = ob0 + DM;
#pragma unroll
  for(int j=0;j<8;j++){
    glob[ob0 + j] = f2bf(accA[j]*li0);
    glob[ob1 + j] = f2bf(accB[j]*li1);
  }
}

// ---------------------------------------------------------------------------
// Triangular-weighted overlap-add: local[b,s,:] = sum_w tri(q_w)*o_w / sum_w tri(q_w)
// Each s belongs to window n=s>>8 (q=s&255, if n<=14) and n-1 (q=(s&255)+256, if n>=1).
// ---------------------------------------------------------------------------
__global__ __launch_bounds__(256) void k_combine(const unsigned short* __restrict__ wso,
                                                 unsigned short* __restrict__ loc){
  const int bid = blockIdx.x;          // B*S
  const int b = bid >> 12, s = bid & 4095;
  const int tid = threadIdx.x;
  const int nhi = s >> 8, sl = s & 255;
  float n0=0.f, n1=0.f, n2=0.f, n3=0.f, den=0.f;
  if(nhi <= 14){
    float tr = 0.5f + (float)sl*(1.0f/511.0f);
    den += tr;
    const unsigned short* p = wso + (size_t)((b*NWIN + nhi)*512 + sl)*DM;
    n0 += tr*f_lo((unsigned int)p[tid]);
    n1 += tr*f_lo((unsigned int)p[tid+256]);
    n2 += tr*f_lo((unsigned int)p[tid+512]);
    n3 += tr*f_lo((unsigned int)p[tid+768]);
  }
  if(nhi >= 1){
    int q2 = sl + 256;
    float tr = 0.5f + (float)q2*(1.0f/511.0f);
    den += tr;
    const unsigned short* p = wso + (size_t)((b*NWIN + nhi-1)*512 + q2)*DM;
    n0 += tr*f_lo((unsigned int)p[tid]);
    n1 += tr*f_lo((unsigned int)p[tid+256]);
    n2 += tr*f_lo((unsigned int)p[tid+512]);
    n3 += tr*f_lo((unsigned int)p[tid+768]);
  }
  float di = 1.0f/den;
  unsigned short* o = loc + (size_t)(b*S_ + s)*DM;
  o[tid]     = f2bf(n0*di);
  o[tid+256] = f2bf(n1*di);
  o[tid+512] = f2bf(n2*di);
  o[tid+768] = f2bf(n3*di);
}

// ---------------------------------------------------------------------------
// Tiled GEMM 64x64, 4x4 micro-tile/thread, K-chunks of 32 staged in LDS.
// A is bf16 (workspace intermediates); W/bias are fp32 (model weights).
// MODE 0: gate GEMM (A = [local|glob], K=2048) + sigmoid + mix epilogue -> mixed (bf16)
// MODE 1: out GEMM (A = mixed, K=1024) + bias -> out (fp32)
// ---------------------------------------------------------------------------
template<int MODE>
__global__ __launch_bounds__(256) void k_gemm(const unsigned short* __restrict__ A0,
                                              const unsigned short* __restrict__ A1,
                                              const float* __restrict__ W,
                                              const float* __restrict__ bias,
                                              const int K,
                                              const unsigned short* __restrict__ loc,
                                              const unsigned short* __restrict__ glo,
                                              const unsigned short* __restrict__ bcb,
                                              unsigned short* __restrict__ outb,
                                              float* __restrict__ outf){
  __shared__ float As[32][72];
  __shared__ float Bs[32][72];
  const int mt = blockIdx.x >> 4, nt = blockIdx.x & 15;
  const int m0 = mt << 6, n0 = nt << 6;
  const int tid = threadIdx.x;
  const int tm = tid & 15, tn = tid >> 4;
  float acc[4][4] = {{0.f,0.f,0.f,0.f},{0.f,0.f,0.f,0.f},{0.f,0.f,0.f,0.f},{0.f,0.f,0.f,0.f}};
  for(int kc=0; kc<K; kc+=32){
    __syncthreads();
    const unsigned short* Asrc = (kc < 1024) ? A0 : A1;
    const int kb = (kc < 1024) ? kc : (kc - 1024);
    {
      int i = tid;
#pragma unroll
      for(int it=0; it<2; it++){
        int mr = i >> 3, kq = i & 7;
        uint2 u = *(const uint2*)(Asrc + (size_t)(m0+mr)*1024 + kb + (kq<<2));
        As[(kq<<2)+0][mr] = f_lo(u.x);
        As[(kq<<2)+1][mr] = f_hi(u.x);
        As[(kq<<2)+2][mr] = f_lo(u.y);
        As[(kq<<2)+3][mr] = f_hi(u.y);
        i += 256;
      }
    }
    {
      int i = tid;
#pragma unroll
      for(int it=0; it<2; it++){
        int kr = i >> 4, nq = i & 15;
        float4 u = *(const float4*)(W + (size_t)(kc+kr)*1024 + n0 + (nq<<2));
        Bs[kr][(nq<<2)+0] = u.x;
        Bs[kr][(nq<<2)+1] = u.y;
        Bs[kr][(nq<<2)+2] = u.z;
        Bs[kr][(nq<<2)+3] = u.w;
        i += 256;
      }
    }
    __syncthreads();
#pragma unroll
    for(int k=0;k<32;k++){
      float4 a  = *(const float4*)&As[k][tm<<2];
      float4 bv = *(const float4*)&Bs[k][tn<<2];
      acc[0][0]+=a.x*bv.x; acc[0][1]+=a.x*bv.y; acc[0][2]+=a.x*bv.z; acc[0][3]+=a.x*bv.w;
      acc[1][0]+=a.y*bv.x; acc[1][1]+=a.y*bv.y; acc[1][2]+=a.y*bv.z; acc[1][3]+=a.y*bv.w;
      acc[2][0]+=a.z*bv.x; acc[2][1]+=a.z*bv.y; acc[2][2]+=a.z*bv.z; acc[2][3]+=a.z*bv.w;
      acc[3][0]+=a.w*bv.x; acc[3][1]+=a.w*bv.y; acc[3][2]+=a.w*bv.z; acc[3][3]+=a.w*bv.w;
    }
  }
  const int mb = m0 + (tm<<2), nb = n0 + (tn<<2);
#pragma unroll
  for(int ii=0;ii<4;ii++){
    size_t row = (size_t)(mb+ii)*1024;
#pragma unroll
    for(int jj=0;jj<4;jj++){
      int nn = nb+jj;
      float v = acc[ii][jj] + bias[nn];
      if(MODE==0){
        float g  = 1.0f/(1.0f + __expf(-v));
        float lv = f_lo((unsigned int)loc[row+nn]);
        float gv = f_lo((unsigned int)glo[row+nn]);
        float bv = f_lo((unsigned int)bcb[row+nn]);
        outb[row+nn] = f2bf(g*lv + (1.0f-g)*gv + bv);
      } else {
        outf[row+nn] = v;
      }
    }
  }
}

extern "C" void kernel_launch(void* const* d_in, const int* in_sizes, int n_in,
                              void* d_out, int out_size, void* d_ws, size_t ws_size,
                              hipStream_t stream){
  const float* x  = (const float*)d_in[0];
  const float* gm = (const float*)d_in[1];
  const float* cw = (const float*)d_in[2];
  const float* cb = (const float*)d_in[3];
  const float* mw = (const float*)d_in[4];
  const float* mb = (const float*)d_in[5];
  const float* ow = (const float*)d_in[6];
  const float* ob = (const float*)d_in[7];
  float* out = (float*)d_out;

  char* ws = (char*)d_ws;
  const size_t SZ = (size_t)B_*S_*DM*2;                 // 16.78 MB per bf16 field
  unsigned short* localb = (unsigned short*)(ws);
  unsigned short* globb  = (unsigned short*)(ws + SZ);
  unsigned short* bcb    = (unsigned short*)(ws + 2*SZ);
  unsigned short* kvb    = (unsigned short*)(ws + 3*SZ);
  unsigned short* wso    = (unsigned short*)(ws + 3*SZ + 524288);
  unsigned short* mixed  = wso;  // wso consumed by k_combine before mix writes here

  k_diffuse<<<1024, 256, 0, stream>>>(x, bcb);
  k_conv   <<<512,  256, 0, stream>>>(x, cw, cb, kvb);
  k_gmem   <<<512,  256, 0, stream>>>(gm, kvb);
  k_gattn  <<<2048, 256, 0, stream>>>(x, kvb, globb);
  k_swin   <<<3840, 256, 0, stream>>>(x, wso);
  k_combine<<<8192, 256, 0, stream>>>(wso, localb);
  k_gemm<0><<<2048, 256, 0, stream>>>(localb, globb, mw, mb, 2048, localb, globb, bcb, mixed, nullptr);
  k_gemm<1><<<2048, 256, 0, stream>>>(mixed, mixed, ow, ob, 1024, nullptr, nullptr, nullptr, nullptr, out);
}

// Round 4
// 695.161 us; speedup vs baseline: 2.6930x; 2.6930x over previous
//
#include <hip/hip_runtime.h>
#include <cstdint>

#define B_   2
#define S_   4096
#define DM   1024
#define NH   8
#define HDIM 128
#define NWIN 15

typedef __attribute__((ext_vector_type(8))) short s8v;   // 8 bf16 (4 VGPRs)
typedef __attribute__((ext_vector_type(4))) float f4v;   // 4 fp32 acc

__device__ __forceinline__ float f_lo(unsigned int u){
  union { unsigned int i; float f; } v; v.i = u << 16; return v.f;
}
__device__ __forceinline__ unsigned short f2bf(float f){
  unsigned int x = __float_as_uint(f);
  x += 0x7fffu + ((x >> 16) & 1u);
  return (unsigned short)(x >> 16);
}

// ---------------------------------------------------------------------------
// Broadcast diffusion: 12 circular 3-tap steps in LDS.
// ---------------------------------------------------------------------------
__global__ __launch_bounds__(256) void k_diffuse(const float* __restrict__ x,
                                                 unsigned short* __restrict__ bc){
  __shared__ float bufA[2][4096];
  __shared__ float bufB[2][4096];
  const int b  = blockIdx.x >> 9;
  const int d0 = (blockIdx.x & 511) * 2;
  const int tid = threadIdx.x;
  float res[32];
#pragma unroll
  for(int k=0;k<32;k++){
    int e = tid + (k<<8); int ch = e>>12; int s = e&4095;
    bufA[ch][s] = x[(size_t)(b*S_+s)*DM + d0 + ch];
    res[k] = 0.f;
  }
  __syncthreads();
#pragma unroll 1
  for(int st=0; st<12; st++){
    const int stride = 1<<st;
    float (*src)[4096] = (st&1) ? bufB : bufA;
    float (*dst)[4096] = (st&1) ? bufA : bufB;
#pragma unroll
    for(int k=0;k<32;k++){
      int e = tid + (k<<8); int ch=e>>12; int s=e&4095;
      float c = src[ch][s] + 0.5f*(src[ch][(s-stride)&4095] + src[ch][(s+stride)&4095]);
      dst[ch][s] = c; res[k] += c;
    }
    __syncthreads();
  }
#pragma unroll
  for(int k=0;k<32;k++){
    int e = tid + (k<<8); int ch=e>>12; int s=e&4095;
    bc[(size_t)(b*S_+s)*DM + d0 + ch] = f2bf(res[k]*(1.0f/13.0f));
  }
}

// ---------------------------------------------------------------------------
// Conv1d(k=4,stride=4) first 64 outputs -> kv[:, :, 0:64, :]
// ---------------------------------------------------------------------------
__global__ __launch_bounds__(256) void k_conv(const float* __restrict__ x,
                                              const float* __restrict__ cw,
                                              const float* __restrict__ cb,
                                              unsigned short* __restrict__ kv){
  __shared__ float xs[4096];
  const int b  = blockIdx.x >> 8;
  const int t  = (blockIdx.x >> 2) & 63;
  const int oc = blockIdx.x & 3;
  const int tid = threadIdx.x;
  const float* xp = x + (size_t)(b*S_ + 4*t)*DM;
  for(int i=tid; i<4096; i+=256){
    xs[((i & 1023)<<2) | (i>>10)] = xp[i];
  }
  __syncthreads();
  const int o = oc*256 + tid;
  float acc = cb[o];
  const float* cwo = cw + (size_t)o*4096;
  for(int d=0; d<1024; d+=2){
    float4 w0 = *(const float4*)(cwo + (d<<2));
    float4 w1 = *(const float4*)(cwo + (d<<2) + 4);
    float4 xa = *(const float4*)&xs[d<<2];
    float4 xb = *(const float4*)&xs[(d<<2)+4];
    acc += xa.x*w0.x + xa.y*w0.y + xa.z*w0.z + xa.w*w0.w
         + xb.x*w1.x + xb.y*w1.y + xb.z*w1.z + xb.w*w1.w;
  }
  const int h = o >> 7, hd = o & 127;
  kv[((size_t)(b*NH + h)*128 + t)*HDIM + hd] = f2bf(acc);
}

__global__ __launch_bounds__(256) void k_gmem(const float* __restrict__ g,
                                              unsigned short* __restrict__ kv){
  int i = blockIdx.x*256 + threadIdx.x;   // 131072 total
  int hd = i & 127, gt = (i>>7)&63, h = (i>>13)&7, b = i>>16;
  kv[((size_t)(b*NH + h)*128 + 64 + gt)*HDIM + hd] = f2bf(g[((size_t)(h*64 + gt))*HDIM + hd]);
}

// ---------------------------------------------------------------------------
// MFMA flash attention. MODE 0: sliding window (8 KV tiles of 64 from x).
// MODE 1: compressed-global (2 KV tiles of 64 from kvb bf16).
// Grid: (480,2) for MODE0 = (n*32 + h*4 + qt, b); (256,2) for MODE1 = (h*32+qt, b).
// Block = 128 q rows, 4 waves x 32 q.
// S^T = K.Q^T; softmax on S^T C-layout (col=q=lane&15); P->LDS [q][t]; O^T=V^T.P^T.
// ---------------------------------------------------------------------------
template<int MODE>
__global__ __launch_bounds__(256) void k_attn(const float* __restrict__ x,
                                              const unsigned short* __restrict__ kvb,
                                              unsigned short* __restrict__ outb){
  __shared__ __align__(16) unsigned short sh[27136];  // 54.3 KB
  constexpr int KSo = 0;      // K-tile [64][136]
  constexpr int VTo = 8704;   // V^T   [128][72]
  constexpr int PSo = 17920;  // P     [128][72]

  const int b = blockIdx.y;
  int h, n, qt, nkt;
  if(MODE==0){ int r = blockIdx.x; n = r>>5; h = (r>>2)&7; qt = r&3; nkt = 8; }
  else       { int r = blockIdx.x; h = r>>5; qt = r&31; n = 0; nkt = 2; }

  const int tid  = threadIdx.x;
  const int wid  = tid>>6, lane = tid&63, quad = lane>>4, tl = lane&15;
  const int sQ   = (MODE==0) ? (n*256 + qt*128) : (qt*128);

  // Q fragments (B-operand layout), pre-scaled
  const float SC = 0.08838834764831845f;
  s8v qf[2][4];
#pragma unroll
  for(int qi=0; qi<2; qi++){
    int qr = sQ + wid*32 + qi*16 + tl;
    const float* qp = x + ((size_t)(b*S_) + qr)*DM + h*HDIM;
#pragma unroll
    for(int ks=0; ks<4; ks++){
      float4 a = *(const float4*)(qp + ks*32 + quad*8);
      float4 c = *(const float4*)(qp + ks*32 + quad*8 + 4);
      qf[qi][ks][0] = (short)f2bf(a.x*SC); qf[qi][ks][1] = (short)f2bf(a.y*SC);
      qf[qi][ks][2] = (short)f2bf(a.z*SC); qf[qi][ks][3] = (short)f2bf(a.w*SC);
      qf[qi][ks][4] = (short)f2bf(c.x*SC); qf[qi][ks][5] = (short)f2bf(c.y*SC);
      qf[qi][ks][6] = (short)f2bf(c.z*SC); qf[qi][ks][7] = (short)f2bf(c.w*SC);
    }
  }

  f4v oacc[8][2];
#pragma unroll
  for(int ht=0; ht<8; ht++){ oacc[ht][0] = (f4v)(0.f); oacc[ht][1] = (f4v)(0.f); }
  float m_[2] = {-1e30f, -1e30f}, l_[2] = {0.f, 0.f};

  for(int kt=0; kt<nkt; kt++){
    __syncthreads();
    if(MODE==0){
      const int k0 = n*256 + kt*64;
      const float* kb = x + ((size_t)(b*S_) + k0)*DM + h*HDIM;
#pragma unroll
      for(int p=0; p<8; p++){
        int t = p*8 + (tid>>5), d0 = (tid&31)*4;
        float4 v = *(const float4*)(kb + (size_t)t*DM + d0);
        ushort4 u = { f2bf(v.x), f2bf(v.y), f2bf(v.z), f2bf(v.w) };
        *(ushort4*)&sh[KSo + t*136 + d0] = u;
      }
      int hd = tid&127, th = tid>>7;
#pragma unroll
      for(int tt=0; tt<8; tt++){
        int t0 = th*32 + tt*4;
        ushort4 u = { f2bf(kb[(size_t)(t0+0)*DM + hd]), f2bf(kb[(size_t)(t0+1)*DM + hd]),
                      f2bf(kb[(size_t)(t0+2)*DM + hd]), f2bf(kb[(size_t)(t0+3)*DM + hd]) };
        *(ushort4*)&sh[VTo + hd*72 + t0] = u;
      }
    } else {
      const unsigned short* kp = kvb + ((size_t)(b*NH+h)*128 + kt*64)*HDIM;
#pragma unroll
      for(int p=0; p<8; p++){
        int t = p*8 + (tid>>5), d0 = (tid&31)*4;
        ushort4 u = *(const ushort4*)(kp + t*HDIM + d0);
        *(ushort4*)&sh[KSo + t*136 + d0] = u;
      }
      int hd = tid&127, th = tid>>7;
#pragma unroll
      for(int tt=0; tt<8; tt++){
        int t0 = th*32 + tt*4;
        ushort4 u = { kp[(t0+0)*HDIM + hd], kp[(t0+1)*HDIM + hd],
                      kp[(t0+2)*HDIM + hd], kp[(t0+3)*HDIM + hd] };
        *(ushort4*)&sh[VTo + hd*72 + t0] = u;
      }
    }
    __syncthreads();

    // S^T[t][q] = K.Q^T
    f4v st[4][2];
#pragma unroll
    for(int tt=0; tt<4; tt++){
      st[tt][0] = (f4v)(0.f); st[tt][1] = (f4v)(0.f);
#pragma unroll
      for(int ks=0; ks<4; ks++){
        s8v af = *(const s8v*)&sh[KSo + (tt*16 + tl)*136 + ks*32 + quad*8];
        st[tt][0] = __builtin_amdgcn_mfma_f32_16x16x32_bf16(af, qf[0][ks], st[tt][0], 0, 0, 0);
        st[tt][1] = __builtin_amdgcn_mfma_f32_16x16x32_bf16(af, qf[1][ks], st[tt][1], 0, 0, 0);
      }
    }

    // online softmax per q column (q = lane&15 per qi)
#pragma unroll
    for(int qi=0; qi<2; qi++){
      float mx = -1e30f;
#pragma unroll
      for(int tt=0; tt<4; tt++)
#pragma unroll
        for(int r=0; r<4; r++) mx = fmaxf(mx, st[tt][qi][r]);
      mx = fmaxf(mx, __shfl_xor(mx, 16));
      mx = fmaxf(mx, __shfl_xor(mx, 32));
      float nm = fmaxf(m_[qi], mx);
      float al = __expf(m_[qi] - nm);
      float ps = 0.f;
#pragma unroll
      for(int tt=0; tt<4; tt++)
#pragma unroll
        for(int r=0; r<4; r++){
          float p = __expf(st[tt][qi][r] - nm);
          st[tt][qi][r] = p; ps += p;
        }
      ps += __shfl_xor(ps, 16);
      ps += __shfl_xor(ps, 32);
      l_[qi] = l_[qi]*al + ps; m_[qi] = nm;
#pragma unroll
      for(int ht=0; ht<8; ht++) oacc[ht][qi] *= al;
      int ql = wid*32 + qi*16 + tl;
#pragma unroll
      for(int tt=0; tt<4; tt++){
        ushort4 u = { f2bf(st[tt][qi][0]), f2bf(st[tt][qi][1]),
                      f2bf(st[tt][qi][2]), f2bf(st[tt][qi][3]) };
        *(ushort4*)&sh[PSo + ql*72 + tt*16 + quad*4] = u;
      }
    }

    // O^T += V^T . P^T   (wave-private P slice; same-wave DS ordering)
#pragma unroll
    for(int kk=0; kk<2; kk++){
      s8v pb0 = *(const s8v*)&sh[PSo + (wid*32 + 0*16 + tl)*72 + kk*32 + quad*8];
      s8v pb1 = *(const s8v*)&sh[PSo + (wid*32 + 1*16 + tl)*72 + kk*32 + quad*8];
#pragma unroll
      for(int ht=0; ht<8; ht++){
        s8v vf = *(const s8v*)&sh[VTo + (ht*16 + tl)*72 + kk*32 + quad*8];
        oacc[ht][0] = __builtin_amdgcn_mfma_f32_16x16x32_bf16(vf, pb0, oacc[ht][0], 0, 0, 0);
        oacc[ht][1] = __builtin_amdgcn_mfma_f32_16x16x32_bf16(vf, pb1, oacc[ht][1], 0, 0, 0);
      }
    }
  }

  // normalize and write out via LDS transpose (overlays KSo/VTo, stride 136)
#pragma unroll
  for(int qi=0; qi<2; qi++){
    float inv = 1.0f/l_[qi];
#pragma unroll
    for(int ht=0; ht<8; ht++) oacc[ht][qi] *= inv;
  }
  __syncthreads();
#pragma unroll
  for(int qi=0; qi<2; qi++){
    int ql = wid*32 + qi*16 + tl;
#pragma unroll
    for(int ht=0; ht<8; ht++){
      ushort4 u = { f2bf(oacc[ht][qi][0]), f2bf(oacc[ht][qi][1]),
                    f2bf(oacc[ht][qi][2]), f2bf(oacc[ht][qi][3]) };
      *(ushort4*)&sh[ql*136 + ht*16 + quad*4] = u;
    }
  }
  __syncthreads();
  {
    int ql = tid>>1, half = tid&1;
    size_t row = (MODE==0) ? (size_t)((b*NWIN + n)*512 + qt*128 + ql)
                           : (size_t)(b*S_ + qt*128 + ql);
    unsigned short* op = outb + row*DM + h*HDIM + half*64;
#pragma unroll
    for(int c=0; c<8; c++){
      uint4 v = *(const uint4*)&sh[ql*136 + half*64 + c*8];
      *(uint4*)(op + c*8) = v;
    }
  }
}

// ---------------------------------------------------------------------------
// Triangular-weighted overlap-add
// ---------------------------------------------------------------------------
__global__ __launch_bounds__(256) void k_combine(const unsigned short* __restrict__ wso,
                                                 unsigned short* __restrict__ loc){
  const int bid = blockIdx.x;          // B*S
  const int b = bid >> 12, s = bid & 4095;
  const int tid = threadIdx.x;
  const int nhi = s >> 8, sl = s & 255;
  float n0=0.f, n1=0.f, n2=0.f, n3=0.f, den=0.f;
  if(nhi <= 14){
    float tr = 0.5f + (float)sl*(1.0f/511.0f);
    den += tr;
    const unsigned short* p = wso + (size_t)((b*NWIN + nhi)*512 + sl)*DM;
    n0 += tr*f_lo((unsigned int)p[tid]);
    n1 += tr*f_lo((unsigned int)p[tid+256]);
    n2 += tr*f_lo((unsigned int)p[tid+512]);
    n3 += tr*f_lo((unsigned int)p[tid+768]);
  }
  if(nhi >= 1){
    int q2 = sl + 256;
    float tr = 0.5f + (float)q2*(1.0f/511.0f);
    den += tr;
    const unsigned short* p = wso + (size_t)((b*NWIN + nhi-1)*512 + q2)*DM;
    n0 += tr*f_lo((unsigned int)p[tid]);
    n1 += tr*f_lo((unsigned int)p[tid+256]);
    n2 += tr*f_lo((unsigned int)p[tid+512]);
    n3 += tr*f_lo((unsigned int)p[tid+768]);
  }
  float di = 1.0f/den;
  unsigned short* o = loc + (size_t)(b*S_ + s)*DM;
  o[tid]     = f2bf(n0*di);
  o[tid+256] = f2bf(n1*di);
  o[tid+512] = f2bf(n2*di);
  o[tid+768] = f2bf(n3*di);
}

// ---------------------------------------------------------------------------
// Weight transpose+convert: W [K][1024] fp32 -> WT [1024][K] bf16 (64x64 tiles)
// ---------------------------------------------------------------------------
__global__ __launch_bounds__(256) void k_wcvt(const float* __restrict__ W,
                                              unsigned short* __restrict__ WT, int K){
  __shared__ float Ls[64][68];
  int kt = blockIdx.x >> 4, nt = blockIdx.x & 15;
  int k0 = kt<<6, n0 = nt<<6;
  int tid = threadIdx.x;
#pragma unroll
  for(int p=0; p<4; p++){
    int r = p*16 + (tid>>4), c4 = (tid&15)*4;
    float4 v = *(const float4*)(W + (size_t)(k0+r)*1024 + n0 + c4);
    *(float4*)&Ls[r][c4] = v;
  }
  __syncthreads();
  int nn = tid>>2, kq = tid&3;
#pragma unroll
  for(int c=0; c<4; c++){
    int k = kq*16 + c*4;
    ushort4 u = { f2bf(Ls[k+0][nn]), f2bf(Ls[k+1][nn]), f2bf(Ls[k+2][nn]), f2bf(Ls[k+3][nn]) };
    *(ushort4*)(WT + (size_t)(n0+nn)*K + k0 + k) = u;
  }
}

// ---------------------------------------------------------------------------
// MFMA GEMM 128x128 tile, BK=64, XOR-swizzled LDS, 4 waves x (64x64 quadrant).
// MODE 0: + sigmoid gate mix epilogue -> mixed (bf16).  MODE 1: + bias -> out fp32.
// ---------------------------------------------------------------------------
template<int MODE>
__global__ __launch_bounds__(256) void k_gemm2(const unsigned short* __restrict__ A0,
                                               const unsigned short* __restrict__ A1,
                                               const unsigned short* __restrict__ WT,
                                               const float* __restrict__ bias,
                                               const unsigned short* __restrict__ loc,
                                               const unsigned short* __restrict__ glo,
                                               const unsigned short* __restrict__ bcb,
                                               unsigned short* __restrict__ outb,
                                               float* __restrict__ outf){
  const int KTOT = (MODE==0) ? 2048 : 1024;
  __shared__ __align__(16) unsigned short As[128*64];
  __shared__ __align__(16) unsigned short Bs[128*64];
  const int mt = blockIdx.x >> 3, nt = blockIdx.x & 7;
  const int m0 = mt<<7, n0 = nt<<7;
  const int tid = threadIdx.x, wid = tid>>6, lane = tid&63, quad = lane>>4, tl = lane&15;
  const int mq = (wid&1)*64, nq = (wid>>1)*64;
  f4v acc[4][4];
#pragma unroll
  for(int i=0;i<4;i++)
#pragma unroll
    for(int j=0;j<4;j++) acc[i][j] = (f4v)(0.f);

  for(int kc=0; kc<KTOT; kc+=64){
    __syncthreads();
    const unsigned short* Ab = (MODE==0 && kc>=1024) ? A1 : A0;
    const int kb = (MODE==0) ? (kc & 1023) : kc;
#pragma unroll
    for(int t=0; t<4; t++){
      int cl = tid + t*256, m = cl>>3, c = cl&7;
      uint4 v = *(const uint4*)(Ab + (size_t)(m0+m)*1024 + kb + c*8);
      *(uint4*)&As[m*64 + ((c ^ (m&7))<<3)] = v;
      uint4 w = *(const uint4*)(WT + (size_t)(n0+m)*KTOT + kc + c*8);
      *(uint4*)&Bs[m*64 + ((c ^ (m&7))<<3)] = w;
    }
    __syncthreads();
#pragma unroll
    for(int ks=0; ks<2; ks++){
      s8v af[4], bf[4];
#pragma unroll
      for(int i=0;i<4;i++){
        int ml = mq + i*16 + tl;
        af[i] = *(const s8v*)&As[ml*64 + (((ks*4+quad) ^ (ml&7))<<3)];
      }
#pragma unroll
      for(int j=0;j<4;j++){
        int nl = nq + j*16 + tl;
        bf[j] = *(const s8v*)&Bs[nl*64 + (((ks*4+quad) ^ (nl&7))<<3)];
      }
#pragma unroll
      for(int i=0;i<4;i++)
#pragma unroll
        for(int j=0;j<4;j++)
          acc[i][j] = __builtin_amdgcn_mfma_f32_16x16x32_bf16(af[i], bf[j], acc[i][j], 0, 0, 0);
    }
  }

#pragma unroll
  for(int i=0;i<4;i++){
#pragma unroll
    for(int r=0;r<4;r++){
      int m = m0 + mq + i*16 + quad*4 + r;
      size_t rowb = (size_t)m * 1024;
#pragma unroll
      for(int j=0;j<4;j++){
        int nn = n0 + nq + j*16 + tl;
        float v = acc[i][j][r] + bias[nn];
        if(MODE==0){
          float g  = 1.0f/(1.0f + __expf(-v));
          float lv = f_lo((unsigned int)loc[rowb+nn]);
          float gv = f_lo((unsigned int)glo[rowb+nn]);
          float bv = f_lo((unsigned int)bcb[rowb+nn]);
          outb[rowb+nn] = f2bf(g*lv + (1.0f-g)*gv + bv);
        } else {
          outf[rowb+nn] = v;
        }
      }
    }
  }
}

extern "C" void kernel_launch(void* const* d_in, const int* in_sizes, int n_in,
                              void* d_out, int out_size, void* d_ws, size_t ws_size,
                              hipStream_t stream){
  const float* x  = (const float*)d_in[0];
  const float* gm = (const float*)d_in[1];
  const float* cw = (const float*)d_in[2];
  const float* cb = (const float*)d_in[3];
  const float* mw = (const float*)d_in[4];
  const float* mb = (const float*)d_in[5];
  const float* ow = (const float*)d_in[6];
  const float* ob = (const float*)d_in[7];
  float* out = (float*)d_out;

  char* ws = (char*)d_ws;
  const size_t SZ = (size_t)B_*S_*DM*2;                 // 16.78 MB per bf16 field
  unsigned short* localb = (unsigned short*)(ws);
  unsigned short* globb  = (unsigned short*)(ws + SZ);
  unsigned short* bcb    = (unsigned short*)(ws + 2*SZ);
  unsigned short* kvb    = (unsigned short*)(ws + 3*SZ);
  unsigned short* wso    = (unsigned short*)(ws + 3*SZ + 524288);
  unsigned short* mixed  = wso;                          // first 16.78 MB of wso region
  unsigned short* wt1    = (unsigned short*)(ws + 3*SZ + 524288 + SZ);            // 4 MB
  unsigned short* wt2    = (unsigned short*)(ws + 3*SZ + 524288 + SZ + 4194304);  // 2 MB

  k_diffuse<<<1024, 256, 0, stream>>>(x, bcb);
  k_conv   <<<512,  256, 0, stream>>>(x, cw, cb, kvb);
  k_gmem   <<<512,  256, 0, stream>>>(gm, kvb);
  k_attn<1><<<dim3(256,2), 256, 0, stream>>>(x, kvb, globb);
  k_attn<0><<<dim3(480,2), 256, 0, stream>>>(x, kvb, wso);
  k_combine<<<8192, 256, 0, stream>>>(wso, localb);
  k_wcvt   <<<512,  256, 0, stream>>>(mw, wt1, 2048);
  k_wcvt   <<<256,  256, 0, stream>>>(ow, wt2, 1024);
  k_gemm2<0><<<512, 256, 0, stream>>>(localb, globb, wt1, mb, localb, globb, bcb, mixed, nullptr);
  k_gemm2<1><<<512, 256, 0, stream>>>(mixed, nullptr, wt2, ob, nullptr, nullptr, nullptr, nullptr, out);
}

// Round 5
// 506.356 us; speedup vs baseline: 3.6971x; 1.3729x over previous
//
#include <hip/hip_runtime.h>
#include <cstdint>

#define B_   2
#define S_   4096
#define DM   1024
#define NH   8
#define HDIM 128
#define NWIN 15

typedef __attribute__((ext_vector_type(8))) short s8v;   // 8 bf16 (4 VGPRs)
typedef __attribute__((ext_vector_type(4))) float f4v;   // 4 fp32 acc

__device__ __forceinline__ float f_lo(unsigned int u){
  union { unsigned int i; float f; } v; v.i = u << 16; return v.f;
}
__device__ __forceinline__ float f_hi(unsigned int u){
  union { unsigned int i; float f; } v; v.i = u & 0xffff0000u; return v.f;
}
__device__ __forceinline__ unsigned short f2bf(float f){
  unsigned int x = __float_as_uint(f);
  x += 0x7fffu + ((x >> 16) & 1u);
  return (unsigned short)(x >> 16);
}
__device__ __forceinline__ unsigned int pack2(float a, float b){
  return (unsigned int)f2bf(a) | ((unsigned int)f2bf(b) << 16);
}

// ---------------------------------------------------------------------------
// Broadcast diffusion: 12 circular 3-tap steps in LDS.
// ---------------------------------------------------------------------------
__global__ __launch_bounds__(256) void k_diffuse(const float* __restrict__ x,
                                                 unsigned short* __restrict__ bc){
  __shared__ float bufA[2][4096];
  __shared__ float bufB[2][4096];
  const int b  = blockIdx.x >> 9;
  const int d0 = (blockIdx.x & 511) * 2;
  const int tid = threadIdx.x;
  float res[32];
#pragma unroll
  for(int k=0;k<32;k++){
    int e = tid + (k<<8); int ch = e>>12; int s = e&4095;
    bufA[ch][s] = x[(size_t)(b*S_+s)*DM + d0 + ch];
    res[k] = 0.f;
  }
  __syncthreads();
#pragma unroll 1
  for(int st=0; st<12; st++){
    const int stride = 1<<st;
    float (*src)[4096] = (st&1) ? bufB : bufA;
    float (*dst)[4096] = (st&1) ? bufA : bufB;
#pragma unroll
    for(int k=0;k<32;k++){
      int e = tid + (k<<8); int ch=e>>12; int s=e&4095;
      float c = src[ch][s] + 0.5f*(src[ch][(s-stride)&4095] + src[ch][(s+stride)&4095]);
      dst[ch][s] = c; res[k] += c;
    }
    __syncthreads();
  }
#pragma unroll
  for(int k=0;k<32;k++){
    int e = tid + (k<<8); int ch=e>>12; int s=e&4095;
    bc[(size_t)(b*S_+s)*DM + d0 + ch] = f2bf(res[k]*(1.0f/13.0f));
  }
}

// ---------------------------------------------------------------------------
// Conv path, MFMA-ified.
// comp[m][o] = cb[o] + sum_dk A[m][dk]*cw[o][dk], m=b*64+t, dk=d*4+k,
// A[m][dk] = x[b][4t+k][d]; cw flat is already [o][dk].
// ---------------------------------------------------------------------------
__global__ __launch_bounds__(256) void k_cwcvt(const float* __restrict__ cw,
                                               unsigned short* __restrict__ cwb){
  size_t i = ((size_t)blockIdx.x*256 + threadIdx.x)*8;   // 4,194,304 total elems
  float4 a = *(const float4*)(cw + i);
  float4 b = *(const float4*)(cw + i + 4);
  uint4 r; r.x = pack2(a.x,a.y); r.y = pack2(a.z,a.w);
  r.z = pack2(b.x,b.y); r.w = pack2(b.z,b.w);
  *(uint4*)(cwb + i) = r;
}

__global__ __launch_bounds__(256) void k_xstage(const float* __restrict__ x,
                                                unsigned short* __restrict__ Asta){
  __shared__ float xs[4][1024];
  const int m = blockIdx.x;            // 0..127
  const int b = m>>6, t = m&63;
  const int tid = threadIdx.x;
  const float* xp = x + (size_t)(b*S_ + 4*t)*DM;
  for(int i=tid; i<4096; i+=256) xs[i>>10][i&1023] = xp[i];
  __syncthreads();
  float v[16];
#pragma unroll
  for(int e=0; e<16; e++) v[e] = xs[e&3][tid*4 + (e>>2)];
  uint4 r0, r1;
  r0.x = pack2(v[0],v[1]);  r0.y = pack2(v[2],v[3]);
  r0.z = pack2(v[4],v[5]);  r0.w = pack2(v[6],v[7]);
  r1.x = pack2(v[8],v[9]);  r1.y = pack2(v[10],v[11]);
  r1.z = pack2(v[12],v[13]); r1.w = pack2(v[14],v[15]);
  unsigned short* op = Asta + (size_t)m*4096 + tid*16;
  *(uint4*)op = r0;
  *(uint4*)(op+8) = r1;
}

// Split-K MFMA GEMM: grid (8 n-tiles, 4 k-splits); each K=1024, BK=64.
__global__ __launch_bounds__(256) void k_gemmconv(const unsigned short* __restrict__ A,
                                                  const unsigned short* __restrict__ Bw,
                                                  float* __restrict__ part){
  __shared__ __align__(16) unsigned short As[128*64];
  __shared__ __align__(16) unsigned short Bs[128*64];
  const int nt = blockIdx.x, kt = blockIdx.y;
  const int n0 = nt<<7;
  const int tid = threadIdx.x, wid = tid>>6, lane = tid&63, quad = lane>>4, tl = lane&15;
  const int mq = (wid&1)*64, nq = (wid>>1)*64;
  f4v acc[4][4];
#pragma unroll
  for(int i=0;i<4;i++)
#pragma unroll
    for(int j=0;j<4;j++) acc[i][j] = (f4v)(0.f);

  for(int kc=kt*1024; kc<kt*1024+1024; kc+=64){
    __syncthreads();
#pragma unroll
    for(int t=0; t<4; t++){
      int cl = tid + t*256, m = cl>>3, c = cl&7;
      uint4 v = *(const uint4*)(A + (size_t)m*4096 + kc + c*8);
      *(uint4*)&As[m*64 + ((c ^ (m&7))<<3)] = v;
      uint4 w = *(const uint4*)(Bw + (size_t)(n0+m)*4096 + kc + c*8);
      *(uint4*)&Bs[m*64 + ((c ^ (m&7))<<3)] = w;
    }
    __syncthreads();
#pragma unroll
    for(int ks=0; ks<2; ks++){
      s8v af[4], bf[4];
#pragma unroll
      for(int i=0;i<4;i++){
        int ml = mq + i*16 + tl;
        af[i] = *(const s8v*)&As[ml*64 + (((ks*4+quad) ^ (ml&7))<<3)];
      }
#pragma unroll
      for(int j=0;j<4;j++){
        int nl = nq + j*16 + tl;
        bf[j] = *(const s8v*)&Bs[nl*64 + (((ks*4+quad) ^ (nl&7))<<3)];
      }
#pragma unroll
      for(int i=0;i<4;i++)
#pragma unroll
        for(int j=0;j<4;j++)
          acc[i][j] = __builtin_amdgcn_mfma_f32_16x16x32_bf16(af[i], bf[j], acc[i][j], 0, 0, 0);
    }
  }
  float* pp = part + (size_t)kt*131072;
#pragma unroll
  for(int i=0;i<4;i++)
#pragma unroll
    for(int r=0;r<4;r++){
      int m = mq + i*16 + quad*4 + r;
#pragma unroll
      for(int j=0;j<4;j++){
        int n = n0 + nq + j*16 + tl;
        pp[m*1024 + n] = acc[i][j][r];
      }
    }
}

__global__ __launch_bounds__(256) void k_convred(const float* __restrict__ part,
                                                 const float* __restrict__ cb,
                                                 unsigned short* __restrict__ kv){
  int i = blockIdx.x*256 + threadIdx.x;   // 131072
  int m = i>>10, o = i&1023;
  float v = part[i] + part[131072+i] + part[262144+i] + part[393216+i] + cb[o];
  int b = m>>6, t = m&63, h = o>>7, hd = o&127;
  kv[((size_t)(b*NH + h)*128 + t)*HDIM + hd] = f2bf(v);
}

__global__ __launch_bounds__(256) void k_gmem(const float* __restrict__ g,
                                              unsigned short* __restrict__ kv){
  int i = blockIdx.x*256 + threadIdx.x;   // 131072 total
  int hd = i & 127, gt = (i>>7)&63, h = (i>>13)&7, b = i>>16;
  kv[((size_t)(b*NH + h)*128 + 64 + gt)*HDIM + hd] = f2bf(g[((size_t)(h*64 + gt))*HDIM + hd]);
}

// ---------------------------------------------------------------------------
// MFMA flash attention. MODE 0: sliding window (8 KV tiles of 64 from x).
// MODE 1: compressed-global (2 KV tiles of 64 from kvb bf16).
// Grid: (480,2) for MODE0 = (n*32 + h*4 + qt, b); (256,2) for MODE1 = (h*32+qt, b).
// ---------------------------------------------------------------------------
template<int MODE>
__global__ __launch_bounds__(256) void k_attn(const float* __restrict__ x,
                                              const unsigned short* __restrict__ kvb,
                                              unsigned short* __restrict__ outb){
  __shared__ __align__(16) unsigned short sh[27136];  // 54.3 KB
  constexpr int KSo = 0;      // K-tile [64][136]
  constexpr int VTo = 8704;   // V^T   [128][72]
  constexpr int PSo = 17920;  // P     [128][72]

  const int b = blockIdx.y;
  int h, n, qt, nkt;
  if(MODE==0){ int r = blockIdx.x; n = r>>5; h = (r>>2)&7; qt = r&3; nkt = 8; }
  else       { int r = blockIdx.x; h = r>>5; qt = r&31; n = 0; nkt = 2; }

  const int tid  = threadIdx.x;
  const int wid  = tid>>6, lane = tid&63, quad = lane>>4, tl = lane&15;
  const int sQ   = (MODE==0) ? (n*256 + qt*128) : (qt*128);

  const float SC = 0.08838834764831845f;
  s8v qf[2][4];
#pragma unroll
  for(int qi=0; qi<2; qi++){
    int qr = sQ + wid*32 + qi*16 + tl;
    const float* qp = x + ((size_t)(b*S_) + qr)*DM + h*HDIM;
#pragma unroll
    for(int ks=0; ks<4; ks++){
      float4 a = *(const float4*)(qp + ks*32 + quad*8);
      float4 c = *(const float4*)(qp + ks*32 + quad*8 + 4);
      qf[qi][ks][0] = (short)f2bf(a.x*SC); qf[qi][ks][1] = (short)f2bf(a.y*SC);
      qf[qi][ks][2] = (short)f2bf(a.z*SC); qf[qi][ks][3] = (short)f2bf(a.w*SC);
      qf[qi][ks][4] = (short)f2bf(c.x*SC); qf[qi][ks][5] = (short)f2bf(c.y*SC);
      qf[qi][ks][6] = (short)f2bf(c.z*SC); qf[qi][ks][7] = (short)f2bf(c.w*SC);
    }
  }

  f4v oacc[8][2];
#pragma unroll
  for(int ht=0; ht<8; ht++){ oacc[ht][0] = (f4v)(0.f); oacc[ht][1] = (f4v)(0.f); }
  float m_[2] = {-1e30f, -1e30f}, l_[2] = {0.f, 0.f};

  for(int kt=0; kt<nkt; kt++){
    __syncthreads();
    if(MODE==0){
      const int k0 = n*256 + kt*64;
      const float* kb = x + ((size_t)(b*S_) + k0)*DM + h*HDIM;
#pragma unroll
      for(int p=0; p<8; p++){
        int t = p*8 + (tid>>5), d0 = (tid&31)*4;
        float4 v = *(const float4*)(kb + (size_t)t*DM + d0);
        ushort4 u = { f2bf(v.x), f2bf(v.y), f2bf(v.z), f2bf(v.w) };
        *(ushort4*)&sh[KSo + t*136 + d0] = u;
      }
      int hd = tid&127, th = tid>>7;
#pragma unroll
      for(int tt=0; tt<8; tt++){
        int t0 = th*32 + tt*4;
        ushort4 u = { f2bf(kb[(size_t)(t0+0)*DM + hd]), f2bf(kb[(size_t)(t0+1)*DM + hd]),
                      f2bf(kb[(size_t)(t0+2)*DM + hd]), f2bf(kb[(size_t)(t0+3)*DM + hd]) };
        *(ushort4*)&sh[VTo + hd*72 + t0] = u;
      }
    } else {
      const unsigned short* kp = kvb + ((size_t)(b*NH+h)*128 + kt*64)*HDIM;
#pragma unroll
      for(int p=0; p<8; p++){
        int t = p*8 + (tid>>5), d0 = (tid&31)*4;
        ushort4 u = *(const ushort4*)(kp + t*HDIM + d0);
        *(ushort4*)&sh[KSo + t*136 + d0] = u;
      }
      int hd = tid&127, th = tid>>7;
#pragma unroll
      for(int tt=0; tt<8; tt++){
        int t0 = th*32 + tt*4;
        ushort4 u = { kp[(t0+0)*HDIM + hd], kp[(t0+1)*HDIM + hd],
                      kp[(t0+2)*HDIM + hd], kp[(t0+3)*HDIM + hd] };
        *(ushort4*)&sh[VTo + hd*72 + t0] = u;
      }
    }
    __syncthreads();

    // S^T[t][q] = K.Q^T
    f4v st[4][2];
#pragma unroll
    for(int tt=0; tt<4; tt++){
      st[tt][0] = (f4v)(0.f); st[tt][1] = (f4v)(0.f);
#pragma unroll
      for(int ks=0; ks<4; ks++){
        s8v af = *(const s8v*)&sh[KSo + (tt*16 + tl)*136 + ks*32 + quad*8];
        st[tt][0] = __builtin_amdgcn_mfma_f32_16x16x32_bf16(af, qf[0][ks], st[tt][0], 0, 0, 0);
        st[tt][1] = __builtin_amdgcn_mfma_f32_16x16x32_bf16(af, qf[1][ks], st[tt][1], 0, 0, 0);
      }
    }

    // online softmax per q column (q = lane&15 per qi)
#pragma unroll
    for(int qi=0; qi<2; qi++){
      float mx = -1e30f;
#pragma unroll
      for(int tt=0; tt<4; tt++)
#pragma unroll
        for(int r=0; r<4; r++) mx = fmaxf(mx, st[tt][qi][r]);
      mx = fmaxf(mx, __shfl_xor(mx, 16));
      mx = fmaxf(mx, __shfl_xor(mx, 32));
      float nm = fmaxf(m_[qi], mx);
      float al = __expf(m_[qi] - nm);
      float ps = 0.f;
#pragma unroll
      for(int tt=0; tt<4; tt++)
#pragma unroll
        for(int r=0; r<4; r++){
          float p = __expf(st[tt][qi][r] - nm);
          st[tt][qi][r] = p; ps += p;
        }
      ps += __shfl_xor(ps, 16);
      ps += __shfl_xor(ps, 32);
      l_[qi] = l_[qi]*al + ps; m_[qi] = nm;
#pragma unroll
      for(int ht=0; ht<8; ht++) oacc[ht][qi] *= al;
      int ql = wid*32 + qi*16 + tl;
#pragma unroll
      for(int tt=0; tt<4; tt++){
        ushort4 u = { f2bf(st[tt][qi][0]), f2bf(st[tt][qi][1]),
                      f2bf(st[tt][qi][2]), f2bf(st[tt][qi][3]) };
        *(ushort4*)&sh[PSo + ql*72 + tt*16 + quad*4] = u;
      }
    }

    // O^T += V^T . P^T
#pragma unroll
    for(int kk=0; kk<2; kk++){
      s8v pb0 = *(const s8v*)&sh[PSo + (wid*32 + 0*16 + tl)*72 + kk*32 + quad*8];
      s8v pb1 = *(const s8v*)&sh[PSo + (wid*32 + 1*16 + tl)*72 + kk*32 + quad*8];
#pragma unroll
      for(int ht=0; ht<8; ht++){
        s8v vf = *(const s8v*)&sh[VTo + (ht*16 + tl)*72 + kk*32 + quad*8];
        oacc[ht][0] = __builtin_amdgcn_mfma_f32_16x16x32_bf16(vf, pb0, oacc[ht][0], 0, 0, 0);
        oacc[ht][1] = __builtin_amdgcn_mfma_f32_16x16x32_bf16(vf, pb1, oacc[ht][1], 0, 0, 0);
      }
    }
  }

  // normalize and write out via LDS transpose
#pragma unroll
  for(int qi=0; qi<2; qi++){
    float inv = 1.0f/l_[qi];
#pragma unroll
    for(int ht=0; ht<8; ht++) oacc[ht][qi] *= inv;
  }
  __syncthreads();
#pragma unroll
  for(int qi=0; qi<2; qi++){
    int ql = wid*32 + qi*16 + tl;
#pragma unroll
    for(int ht=0; ht<8; ht++){
      ushort4 u = { f2bf(oacc[ht][qi][0]), f2bf(oacc[ht][qi][1]),
                    f2bf(oacc[ht][qi][2]), f2bf(oacc[ht][qi][3]) };
      *(ushort4*)&sh[ql*136 + ht*16 + quad*4] = u;
    }
  }
  __syncthreads();
  {
    int ql = tid>>1, half = tid&1;
    size_t row = (MODE==0) ? (size_t)((b*NWIN + n)*512 + qt*128 + ql)
                           : (size_t)(b*S_ + qt*128 + ql);
    unsigned short* op = outb + row*DM + h*HDIM + half*64;
#pragma unroll
    for(int c=0; c<8; c++){
      uint4 v = *(const uint4*)&sh[ql*136 + half*64 + c*8];
      *(uint4*)(op + c*8) = v;
    }
  }
}

// ---------------------------------------------------------------------------
// Triangular-weighted overlap-add (vectorized: uint2 per window read)
// ---------------------------------------------------------------------------
__global__ __launch_bounds__(256) void k_combine(const unsigned short* __restrict__ wso,
                                                 unsigned short* __restrict__ loc){
  const int bid = blockIdx.x;          // B*S
  const int b = bid >> 12, s = bid & 4095;
  const int tid = threadIdx.x;
  const int nhi = s >> 8, sl = s & 255;
  const int c0 = tid*4;
  float n0=0.f, n1=0.f, n2=0.f, n3=0.f, den=0.f;
  if(nhi <= 14){
    float tr = 0.5f + (float)sl*(1.0f/511.0f);
    den += tr;
    uint2 u = *(const uint2*)(wso + (size_t)((b*NWIN + nhi)*512 + sl)*DM + c0);
    n0 += tr*f_lo(u.x); n1 += tr*f_hi(u.x); n2 += tr*f_lo(u.y); n3 += tr*f_hi(u.y);
  }
  if(nhi >= 1){
    int q2 = sl + 256;
    float tr = 0.5f + (float)q2*(1.0f/511.0f);
    den += tr;
    uint2 u = *(const uint2*)(wso + (size_t)((b*NWIN + nhi-1)*512 + q2)*DM + c0);
    n0 += tr*f_lo(u.x); n1 += tr*f_hi(u.x); n2 += tr*f_lo(u.y); n3 += tr*f_hi(u.y);
  }
  float di = 1.0f/den;
  uint2 o; o.x = pack2(n0*di, n1*di); o.y = pack2(n2*di, n3*di);
  *(uint2*)(loc + (size_t)(b*S_ + s)*DM + c0) = o;
}

// ---------------------------------------------------------------------------
// Weight transpose+convert: W [K][1024] fp32 -> WT [1024][K] bf16 (64x64 tiles)
// ---------------------------------------------------------------------------
__global__ __launch_bounds__(256) void k_wcvt(const float* __restrict__ W,
                                              unsigned short* __restrict__ WT, int K){
  __shared__ float Ls[64][68];
  int kt = blockIdx.x >> 4, nt = blockIdx.x & 15;
  int k0 = kt<<6, n0 = nt<<6;
  int tid = threadIdx.x;
#pragma unroll
  for(int p=0; p<4; p++){
    int r = p*16 + (tid>>4), c4 = (tid&15)*4;
    float4 v = *(const float4*)(W + (size_t)(k0+r)*1024 + n0 + c4);
    *(float4*)&Ls[r][c4] = v;
  }
  __syncthreads();
  int nn = tid>>2, kq = tid&3;
#pragma unroll
  for(int c=0; c<4; c++){
    int k = kq*16 + c*4;
    ushort4 u = { f2bf(Ls[k+0][nn]), f2bf(Ls[k+1][nn]), f2bf(Ls[k+2][nn]), f2bf(Ls[k+3][nn]) };
    *(ushort4*)(WT + (size_t)(n0+nn)*K + k0 + k) = u;
  }
}

// ---------------------------------------------------------------------------
// MFMA GEMM 128x128 tile, BK=64, XOR-swizzled LDS, 4 waves x (64x64 quadrant).
// MODE 0: + sigmoid gate mix epilogue -> mixed (bf16).  MODE 1: + bias -> out fp32.
// ---------------------------------------------------------------------------
template<int MODE>
__global__ __launch_bounds__(256) void k_gemm2(const unsigned short* __restrict__ A0,
                                               const unsigned short* __restrict__ A1,
                                               const unsigned short* __restrict__ WT,
                                               const float* __restrict__ bias,
                                               const unsigned short* __restrict__ loc,
                                               const unsigned short* __restrict__ glo,
                                               const unsigned short* __restrict__ bcb,
                                               unsigned short* __restrict__ outb,
                                               float* __restrict__ outf){
  const int KTOT = (MODE==0) ? 2048 : 1024;
  __shared__ __align__(16) unsigned short As[128*64];
  __shared__ __align__(16) unsigned short Bs[128*64];
  const int mt = blockIdx.x >> 3, nt = blockIdx.x & 7;
  const int m0 = mt<<7, n0 = nt<<7;
  const int tid = threadIdx.x, wid = tid>>6, lane = tid&63, quad = lane>>4, tl = lane&15;
  const int mq = (wid&1)*64, nq = (wid>>1)*64;
  f4v acc[4][4];
#pragma unroll
  for(int i=0;i<4;i++)
#pragma unroll
    for(int j=0;j<4;j++) acc[i][j] = (f4v)(0.f);

  for(int kc=0; kc<KTOT; kc+=64){
    __syncthreads();
    const unsigned short* Ab = (MODE==0 && kc>=1024) ? A1 : A0;
    const int kb = (MODE==0) ? (kc & 1023) : kc;
#pragma unroll
    for(int t=0; t<4; t++){
      int cl = tid + t*256, m = cl>>3, c = cl&7;
      uint4 v = *(const uint4*)(Ab + (size_t)(m0+m)*1024 + kb + c*8);
      *(uint4*)&As[m*64 + ((c ^ (m&7))<<3)] = v;
      uint4 w = *(const uint4*)(WT + (size_t)(n0+m)*KTOT + kc + c*8);
      *(uint4*)&Bs[m*64 + ((c ^ (m&7))<<3)] = w;
    }
    __syncthreads();
#pragma unroll
    for(int ks=0; ks<2; ks++){
      s8v af[4], bf[4];
#pragma unroll
      for(int i=0;i<4;i++){
        int ml = mq + i*16 + tl;
        af[i] = *(const s8v*)&As[ml*64 + (((ks*4+quad) ^ (ml&7))<<3)];
      }
#pragma unroll
      for(int j=0;j<4;j++){
        int nl = nq + j*16 + tl;
        bf[j] = *(const s8v*)&Bs[nl*64 + (((ks*4+quad) ^ (nl&7))<<3)];
      }
#pragma unroll
      for(int i=0;i<4;i++)
#pragma unroll
        for(int j=0;j<4;j++)
          acc[i][j] = __builtin_amdgcn_mfma_f32_16x16x32_bf16(af[i], bf[j], acc[i][j], 0, 0, 0);
    }
  }

#pragma unroll
  for(int i=0;i<4;i++){
#pragma unroll
    for(int r=0;r<4;r++){
      int m = m0 + mq + i*16 + quad*4 + r;
      size_t rowb = (size_t)m * 1024;
#pragma unroll
      for(int j=0;j<4;j++){
        int nn = n0 + nq + j*16 + tl;
        float v = acc[i][j][r] + bias[nn];
        if(MODE==0){
          float g  = 1.0f/(1.0f + __expf(-v));
          float lv = f_lo((unsigned int)loc[rowb+nn]);
          float gv = f_lo((unsigned int)glo[rowb+nn]);
          float bv = f_lo((unsigned int)bcb[rowb+nn]);
          outb[rowb+nn] = f2bf(g*lv + (1.0f-g)*gv + bv);
        } else {
          outf[rowb+nn] = v;
        }
      }
    }
  }
}

extern "C" void kernel_launch(void* const* d_in, const int* in_sizes, int n_in,
                              void* d_out, int out_size, void* d_ws, size_t ws_size,
                              hipStream_t stream){
  const float* x  = (const float*)d_in[0];
  const float* gm = (const float*)d_in[1];
  const float* cw = (const float*)d_in[2];
  const float* cb = (const float*)d_in[3];
  const float* mw = (const float*)d_in[4];
  const float* mb = (const float*)d_in[5];
  const float* ow = (const float*)d_in[6];
  const float* ob = (const float*)d_in[7];
  float* out = (float*)d_out;

  char* ws = (char*)d_ws;
  const size_t SZ = (size_t)B_*S_*DM*2;                 // 16.78 MB per bf16 field
  unsigned short* localb = (unsigned short*)(ws);
  unsigned short* globb  = (unsigned short*)(ws + SZ);
  unsigned short* bcb    = (unsigned short*)(ws + 2*SZ);
  unsigned short* kvb    = (unsigned short*)(ws + 3*SZ);
  unsigned short* wso    = (unsigned short*)(ws + 3*SZ + 524288);
  unsigned short* mixed  = wso;                          // first 16.78 MB of wso region
  unsigned short* wt1    = (unsigned short*)(ws + 3*SZ + 524288 + SZ);            // 4 MB
  unsigned short* wt2    = (unsigned short*)(ws + 3*SZ + 524288 + SZ + 4194304);  // 2 MB
  // conv-path scratch overlays localb (conv completes before k_combine writes it)
  unsigned short* cwb    = (unsigned short*)(ws);               // 8 MB bf16 [1024][4096]
  unsigned short* asta   = (unsigned short*)(ws + 8388608);     // 1 MB bf16 [128][4096]
  float*          cpart  = (float*)        (ws + 9437184);      // 2 MB fp32 [4][128][1024]

  k_cwcvt   <<<2048, 256, 0, stream>>>(cw, cwb);
  k_xstage  <<<128,  256, 0, stream>>>(x, asta);
  k_gemmconv<<<dim3(8,4), 256, 0, stream>>>(asta, cwb, cpart);
  k_convred <<<512,  256, 0, stream>>>(cpart, cb, kvb);
  k_gmem    <<<512,  256, 0, stream>>>(gm, kvb);
  k_diffuse <<<1024, 256, 0, stream>>>(x, bcb);
  k_attn<1> <<<dim3(256,2), 256, 0, stream>>>(x, kvb, globb);
  k_attn<0> <<<dim3(480,2), 256, 0, stream>>>(x, kvb, wso);
  k_combine <<<8192, 256, 0, stream>>>(wso, localb);
  k_wcvt    <<<512,  256, 0, stream>>>(mw, wt1, 2048);
  k_wcvt    <<<256,  256, 0, stream>>>(ow, wt2, 1024);
  k_gemm2<0><<<512, 256, 0, stream>>>(localb, globb, wt1, mb, localb, globb, bcb, mixed, nullptr);
  k_gemm2<1><<<512, 256, 0, stream>>>(mixed, nullptr, wt2, ob, nullptr, nullptr, nullptr, nullptr, out);
}

// Round 6
// 436.881 us; speedup vs baseline: 4.2850x; 1.1590x over previous
//
#include <hip/hip_runtime.h>
#include <cstdint>

#define B_   2
#define S_   4096
#define DM   1024
#define NH   8
#define HDIM 128
#define NWIN 15

typedef __attribute__((ext_vector_type(8))) short s8v;   // 8 bf16 (4 VGPRs)
typedef __attribute__((ext_vector_type(4))) float f4v;   // 4 fp32 acc

__device__ __forceinline__ float f_lo(unsigned int u){
  union { unsigned int i; float f; } v; v.i = u << 16; return v.f;
}
__device__ __forceinline__ float f_hi(unsigned int u){
  union { unsigned int i; float f; } v; v.i = u & 0xffff0000u; return v.f;
}
__device__ __forceinline__ unsigned short f2bf(float f){
  unsigned int x = __float_as_uint(f);
  x += 0x7fffu + ((x >> 16) & 1u);
  return (unsigned short)(x >> 16);
}
__device__ __forceinline__ unsigned int pack2(float a, float b){
  return (unsigned int)f2bf(a) | ((unsigned int)f2bf(b) << 16);
}

// ---------------------------------------------------------------------------
// Generic fp32 -> bf16 convert (8 elems/thread). Used for cw (2048 blocks)
// and x (4096 blocks).
// ---------------------------------------------------------------------------
__global__ __launch_bounds__(256) void k_cvtbf(const float* __restrict__ src,
                                               unsigned short* __restrict__ dst){
  size_t i = ((size_t)blockIdx.x*256 + threadIdx.x)*8;
  float4 a = *(const float4*)(src + i);
  float4 b = *(const float4*)(src + i + 4);
  uint4 r; r.x = pack2(a.x,a.y); r.y = pack2(a.z,a.w);
  r.z = pack2(b.x,b.y); r.w = pack2(b.z,b.w);
  *(uint4*)(dst + i) = r;
}

// ---------------------------------------------------------------------------
// fp32 transpose: x [b][s][1024] -> xT [b][1024][s].  64x64 tiles.
// ---------------------------------------------------------------------------
__global__ __launch_bounds__(256) void k_xposef(const float* __restrict__ x,
                                                float* __restrict__ xT){
  __shared__ float Ls[64][68];
  const int bid = blockIdx.x;             // b*1024 + st*16 + dt
  const int b = bid>>10, r = bid&1023, st = r>>4, dt = r&15;
  const int s0 = st*64, d0 = dt*64;
  const int tid = threadIdx.x;
#pragma unroll
  for(int p=0;p<4;p++){
    int rr = p*16 + (tid>>4), c4 = (tid&15)*4;
    *(float4*)&Ls[rr][c4] = *(const float4*)(x + ((size_t)(b*S_)+s0+rr)*DM + d0 + c4);
  }
  __syncthreads();
#pragma unroll
  for(int p=0;p<4;p++){
    int dr = p*16 + (tid>>4), c4 = (tid&15)*4;
    float4 v = { Ls[c4+0][dr], Ls[c4+1][dr], Ls[c4+2][dr], Ls[c4+3][dr] };
    *(float4*)(xT + ((size_t)(b*DM)+d0+dr)*S_ + s0 + c4) = v;
  }
}

// ---------------------------------------------------------------------------
// Diffusion in transposed space: block = (b, 2 d-rows), all I/O contiguous in s.
// cur kept in registers (LDS only for cross-thread neighbors).
// ---------------------------------------------------------------------------
__global__ __launch_bounds__(256) void k_diffuseT(const float* __restrict__ xT,
                                                  unsigned short* __restrict__ bcT){
  __shared__ float bufA[2][4096];
  __shared__ float bufB[2][4096];
  const int b  = blockIdx.x >> 9;
  const int d0 = (blockIdx.x & 511) * 2;
  const int tid = threadIdx.x;
  float cur[32], res[32];
#pragma unroll
  for(int k=0;k<32;k++){
    int e = tid + (k<<8); int ch = e>>12; int s = e&4095;
    float v = xT[((size_t)(b*DM)+d0+ch)*S_ + s];
    cur[k] = v; res[k] = 0.f; bufA[ch][s] = v;
  }
  __syncthreads();
#pragma unroll 1
  for(int st=0; st<12; st++){
    const int stride = 1<<st;
    float (*src)[4096] = (st&1) ? bufB : bufA;
    float (*dst)[4096] = (st&1) ? bufA : bufB;
#pragma unroll
    for(int k=0;k<32;k++){
      int e = tid + (k<<8); int ch=e>>12; int s=e&4095;
      float c = cur[k] + 0.5f*(src[ch][(s-stride)&4095] + src[ch][(s+stride)&4095]);
      dst[ch][s] = c; cur[k] = c; res[k] += c;
    }
    __syncthreads();
  }
#pragma unroll
  for(int k=0;k<32;k++){
    int e = tid + (k<<8); int ch=e>>12; int s=e&4095;
    bcT[((size_t)(b*DM)+d0+ch)*S_ + s] = f2bf(res[k]*(1.0f/13.0f));
  }
}

// ---------------------------------------------------------------------------
// bf16 transpose back: bcT [b][1024][s] -> bc [b][s][1024]. 64x64 tiles.
// ---------------------------------------------------------------------------
__global__ __launch_bounds__(256) void k_bcxpose(const unsigned short* __restrict__ bcT,
                                                 unsigned short* __restrict__ bc){
  __shared__ unsigned short Ls[64*72];
  const int bid = blockIdx.x;             // b*1024 + st*16 + dt
  const int b = bid>>10, r = bid&1023, st = r>>4, dt = r&15;
  const int s0 = st*64, d0 = dt*64;
  const int tid = threadIdx.x;
#pragma unroll
  for(int t=0;t<2;t++){
    int cl = tid + t*256; int dr = cl>>3, c = cl&7;
    *(uint4*)&Ls[dr*72 + c*8] = *(const uint4*)(bcT + ((size_t)(b*DM)+d0+dr)*S_ + s0 + c*8);
  }
  __syncthreads();
#pragma unroll
  for(int t=0;t<2;t++){
    int cl = tid + t*256; int sr = cl>>3, c = cl&7;
    unsigned short tmp[8];
#pragma unroll
    for(int j=0;j<8;j++) tmp[j] = Ls[(c*8+j)*72 + sr];
    *(uint4*)(bc + ((size_t)(b*S_)+s0+sr)*DM + d0 + c*8) = *(const uint4*)tmp;
  }
}

// ---------------------------------------------------------------------------
// Conv path (MFMA), unchanged from R5.
// ---------------------------------------------------------------------------
__global__ __launch_bounds__(256) void k_xstage(const float* __restrict__ x,
                                                unsigned short* __restrict__ Asta){
  __shared__ float xs[4][1024];
  const int m = blockIdx.x;            // 0..127
  const int b = m>>6, t = m&63;
  const int tid = threadIdx.x;
  const float* xp = x + (size_t)(b*S_ + 4*t)*DM;
  for(int i=tid; i<4096; i+=256) xs[i>>10][i&1023] = xp[i];
  __syncthreads();
  float v[16];
#pragma unroll
  for(int e=0; e<16; e++) v[e] = xs[e&3][tid*4 + (e>>2)];
  uint4 r0, r1;
  r0.x = pack2(v[0],v[1]);  r0.y = pack2(v[2],v[3]);
  r0.z = pack2(v[4],v[5]);  r0.w = pack2(v[6],v[7]);
  r1.x = pack2(v[8],v[9]);  r1.y = pack2(v[10],v[11]);
  r1.z = pack2(v[12],v[13]); r1.w = pack2(v[14],v[15]);
  unsigned short* op = Asta + (size_t)m*4096 + tid*16;
  *(uint4*)op = r0;
  *(uint4*)(op+8) = r1;
}

__global__ __launch_bounds__(256) void k_gemmconv(const unsigned short* __restrict__ A,
                                                  const unsigned short* __restrict__ Bw,
                                                  float* __restrict__ part){
  __shared__ __align__(16) unsigned short As[128*64];
  __shared__ __align__(16) unsigned short Bs[128*64];
  const int nt = blockIdx.x, kt = blockIdx.y;
  const int n0 = nt<<7;
  const int tid = threadIdx.x, wid = tid>>6, lane = tid&63, quad = lane>>4, tl = lane&15;
  const int mq = (wid&1)*64, nq = (wid>>1)*64;
  f4v acc[4][4];
#pragma unroll
  for(int i=0;i<4;i++)
#pragma unroll
    for(int j=0;j<4;j++) acc[i][j] = (f4v)(0.f);

  for(int kc=kt*1024; kc<kt*1024+1024; kc+=64){
    __syncthreads();
#pragma unroll
    for(int t=0; t<4; t++){
      int cl = tid + t*256, m = cl>>3, c = cl&7;
      uint4 v = *(const uint4*)(A + (size_t)m*4096 + kc + c*8);
      *(uint4*)&As[m*64 + ((c ^ (m&7))<<3)] = v;
      uint4 w = *(const uint4*)(Bw + (size_t)(n0+m)*4096 + kc + c*8);
      *(uint4*)&Bs[m*64 + ((c ^ (m&7))<<3)] = w;
    }
    __syncthreads();
#pragma unroll
    for(int ks=0; ks<2; ks++){
      s8v af[4], bf[4];
#pragma unroll
      for(int i=0;i<4;i++){
        int ml = mq + i*16 + tl;
        af[i] = *(const s8v*)&As[ml*64 + (((ks*4+quad) ^ (ml&7))<<3)];
      }
#pragma unroll
      for(int j=0;j<4;j++){
        int nl = nq + j*16 + tl;
        bf[j] = *(const s8v*)&Bs[nl*64 + (((ks*4+quad) ^ (nl&7))<<3)];
      }
#pragma unroll
      for(int i=0;i<4;i++)
#pragma unroll
        for(int j=0;j<4;j++)
          acc[i][j] = __builtin_amdgcn_mfma_f32_16x16x32_bf16(af[i], bf[j], acc[i][j], 0, 0, 0);
    }
  }
  float* pp = part + (size_t)kt*131072;
#pragma unroll
  for(int i=0;i<4;i++)
#pragma unroll
    for(int r=0;r<4;r++){
      int m = mq + i*16 + quad*4 + r;
#pragma unroll
      for(int j=0;j<4;j++){
        int n = n0 + nq + j*16 + tl;
        pp[m*1024 + n] = acc[i][j][r];
      }
    }
}

__global__ __launch_bounds__(256) void k_convred(const float* __restrict__ part,
                                                 const float* __restrict__ cb,
                                                 unsigned short* __restrict__ kv){
  int i = blockIdx.x*256 + threadIdx.x;   // 131072
  int m = i>>10, o = i&1023;
  float v = part[i] + part[131072+i] + part[262144+i] + part[393216+i] + cb[o];
  int b = m>>6, t = m&63, h = o>>7, hd = o&127;
  kv[((size_t)(b*NH + h)*128 + t)*HDIM + hd] = f2bf(v);
}

__global__ __launch_bounds__(256) void k_gmem(const float* __restrict__ g,
                                              unsigned short* __restrict__ kv){
  int i = blockIdx.x*256 + threadIdx.x;   // 131072 total
  int hd = i & 127, gt = (i>>7)&63, h = (i>>13)&7, b = i>>16;
  kv[((size_t)(b*NH + h)*128 + 64 + gt)*HDIM + hd] = f2bf(g[((size_t)(h*64 + gt))*HDIM + hd]);
}

// ---------------------------------------------------------------------------
// MFMA flash attention, bf16 inputs (no conversions in hot loop).
// K-tile LDS: [64][128] XOR-swizzled (chunk c at c^(row&7)), no pad.
// Score scale applied post-MFMA. LDS total 53.2 KB -> 3 blocks/CU.
// ---------------------------------------------------------------------------
template<int MODE>
__global__ __launch_bounds__(256) void k_attn(const unsigned short* __restrict__ xb,
                                              const unsigned short* __restrict__ kvb,
                                              unsigned short* __restrict__ outb){
  __shared__ __align__(16) unsigned short sh[26624];  // 53.2 KB
  constexpr int KSo = 0;      // K-tile [64][128] swizzled
  constexpr int VTo = 8192;   // V^T   [128][72]
  constexpr int PSo = 17408;  // P     [128][72]

  const int b = blockIdx.y;
  int h, n, qt, nkt;
  if(MODE==0){ int r = blockIdx.x; n = r>>5; h = (r>>2)&7; qt = r&3; nkt = 8; }
  else       { int r = blockIdx.x; h = r>>5; qt = r&31; n = 0; nkt = 2; }

  const int tid  = threadIdx.x;
  const int wid  = tid>>6, lane = tid&63, quad = lane>>4, tl = lane&15;
  const int sQ   = (MODE==0) ? (n*256 + qt*128) : (qt*128);

  s8v qf[2][4];
#pragma unroll
  for(int qi=0; qi<2; qi++){
    int qr = sQ + wid*32 + qi*16 + tl;
    const unsigned short* qp = xb + ((size_t)(b*S_) + qr)*DM + h*HDIM;
#pragma unroll
    for(int ks=0; ks<4; ks++)
      qf[qi][ks] = *(const s8v*)(qp + ks*32 + quad*8);
  }

  f4v oacc[8][2];
#pragma unroll
  for(int ht=0; ht<8; ht++){ oacc[ht][0] = (f4v)(0.f); oacc[ht][1] = (f4v)(0.f); }
  float m_[2] = {-1e30f, -1e30f}, l_[2] = {0.f, 0.f};

  for(int kt=0; kt<nkt; kt++){
    __syncthreads();
    const unsigned short* kp = (MODE==0)
        ? xb + ((size_t)(b*S_) + n*256 + kt*64)*DM + h*HDIM
        : kvb + ((size_t)(b*NH+h)*128 + kt*64)*HDIM;
    const int kstride = (MODE==0) ? DM : HDIM;
    // K-tile: 1024 chunks of 8 ushorts, swizzled store
#pragma unroll
    for(int t=0; t<4; t++){
      int cl = tid + t*256, m = cl>>4, c = cl&15;
      uint4 v = *(const uint4*)(kp + (size_t)m*kstride + c*8);
      *(uint4*)&sh[KSo + m*128 + ((c ^ (m&7))<<3)] = v;
    }
    // V^T gather (bf16 scalar loads, coalesced per row)
    {
      int hd = tid&127, th = tid>>7;
#pragma unroll
      for(int tt=0; tt<8; tt++){
        int t0 = th*32 + tt*4;
        ushort4 u = { kp[(size_t)(t0+0)*kstride + hd], kp[(size_t)(t0+1)*kstride + hd],
                      kp[(size_t)(t0+2)*kstride + hd], kp[(size_t)(t0+3)*kstride + hd] };
        *(ushort4*)&sh[VTo + hd*72 + t0] = u;
      }
    }
    __syncthreads();

    // S^T[t][q] = K.Q^T
    f4v st[4][2];
#pragma unroll
    for(int tt=0; tt<4; tt++){
      st[tt][0] = (f4v)(0.f); st[tt][1] = (f4v)(0.f);
      int row = tt*16 + tl;
#pragma unroll
      for(int ks=0; ks<4; ks++){
        s8v af = *(const s8v*)&sh[KSo + row*128 + (((ks*4+quad) ^ (row&7))<<3)];
        st[tt][0] = __builtin_amdgcn_mfma_f32_16x16x32_bf16(af, qf[0][ks], st[tt][0], 0, 0, 0);
        st[tt][1] = __builtin_amdgcn_mfma_f32_16x16x32_bf16(af, qf[1][ks], st[tt][1], 0, 0, 0);
      }
    }

    const float SC = 0.08838834764831845f;
    // online softmax per q column (q = lane&15 per qi)
#pragma unroll
    for(int qi=0; qi<2; qi++){
      float mx = -1e30f;
#pragma unroll
      for(int tt=0; tt<4; tt++)
#pragma unroll
        for(int r=0; r<4; r++){
          float v = st[tt][qi][r]*SC;
          st[tt][qi][r] = v;
          mx = fmaxf(mx, v);
        }
      mx = fmaxf(mx, __shfl_xor(mx, 16));
      mx = fmaxf(mx, __shfl_xor(mx, 32));
      float nm = fmaxf(m_[qi], mx);
      float al = __expf(m_[qi] - nm);
      float ps = 0.f;
#pragma unroll
      for(int tt=0; tt<4; tt++)
#pragma unroll
        for(int r=0; r<4; r++){
          float p = __expf(st[tt][qi][r] - nm);
          st[tt][qi][r] = p; ps += p;
        }
      ps += __shfl_xor(ps, 16);
      ps += __shfl_xor(ps, 32);
      l_[qi] = l_[qi]*al + ps; m_[qi] = nm;
#pragma unroll
      for(int ht=0; ht<8; ht++) oacc[ht][qi] *= al;
      int ql = wid*32 + qi*16 + tl;
#pragma unroll
      for(int tt=0; tt<4; tt++){
        ushort4 u = { f2bf(st[tt][qi][0]), f2bf(st[tt][qi][1]),
                      f2bf(st[tt][qi][2]), f2bf(st[tt][qi][3]) };
        *(ushort4*)&sh[PSo + ql*72 + tt*16 + quad*4] = u;
      }
    }

    // O^T += V^T . P^T
#pragma unroll
    for(int kk=0; kk<2; kk++){
      s8v pb0 = *(const s8v*)&sh[PSo + (wid*32 + 0*16 + tl)*72 + kk*32 + quad*8];
      s8v pb1 = *(const s8v*)&sh[PSo + (wid*32 + 1*16 + tl)*72 + kk*32 + quad*8];
#pragma unroll
      for(int ht=0; ht<8; ht++){
        s8v vf = *(const s8v*)&sh[VTo + (ht*16 + tl)*72 + kk*32 + quad*8];
        oacc[ht][0] = __builtin_amdgcn_mfma_f32_16x16x32_bf16(vf, pb0, oacc[ht][0], 0, 0, 0);
        oacc[ht][1] = __builtin_amdgcn_mfma_f32_16x16x32_bf16(vf, pb1, oacc[ht][1], 0, 0, 0);
      }
    }
  }

  // normalize and write out via LDS transpose (overlays KS/VT, stride 136)
#pragma unroll
  for(int qi=0; qi<2; qi++){
    float inv = 1.0f/l_[qi];
#pragma unroll
    for(int ht=0; ht<8; ht++) oacc[ht][qi] *= inv;
  }
  __syncthreads();
#pragma unroll
  for(int qi=0; qi<2; qi++){
    int ql = wid*32 + qi*16 + tl;
#pragma unroll
    for(int ht=0; ht<8; ht++){
      ushort4 u = { f2bf(oacc[ht][qi][0]), f2bf(oacc[ht][qi][1]),
                    f2bf(oacc[ht][qi][2]), f2bf(oacc[ht][qi][3]) };
      *(ushort4*)&sh[ql*136 + ht*16 + quad*4] = u;
    }
  }
  __syncthreads();
  {
    int ql = tid>>1, half = tid&1;
    size_t row = (MODE==0) ? (size_t)((b*NWIN + n)*512 + qt*128 + ql)
                           : (size_t)(b*S_ + qt*128 + ql);
    unsigned short* op = outb + row*DM + h*HDIM + half*64;
#pragma unroll
    for(int c=0; c<8; c++){
      uint4 v = *(const uint4*)&sh[ql*136 + half*64 + c*8];
      *(uint4*)(op + c*8) = v;
    }
  }
}

// ---------------------------------------------------------------------------
// Triangular-weighted overlap-add
// ---------------------------------------------------------------------------
__global__ __launch_bounds__(256) void k_combine(const unsigned short* __restrict__ wso,
                                                 unsigned short* __restrict__ loc){
  const int bid = blockIdx.x;          // B*S
  const int b = bid >> 12, s = bid & 4095;
  const int tid = threadIdx.x;
  const int nhi = s >> 8, sl = s & 255;
  const int c0 = tid*4;
  float n0=0.f, n1=0.f, n2=0.f, n3=0.f, den=0.f;
  if(nhi <= 14){
    float tr = 0.5f + (float)sl*(1.0f/511.0f);
    den += tr;
    uint2 u = *(const uint2*)(wso + (size_t)((b*NWIN + nhi)*512 + sl)*DM + c0);
    n0 += tr*f_lo(u.x); n1 += tr*f_hi(u.x); n2 += tr*f_lo(u.y); n3 += tr*f_hi(u.y);
  }
  if(nhi >= 1){
    int q2 = sl + 256;
    float tr = 0.5f + (float)q2*(1.0f/511.0f);
    den += tr;
    uint2 u = *(const uint2*)(wso + (size_t)((b*NWIN + nhi-1)*512 + q2)*DM + c0);
    n0 += tr*f_lo(u.x); n1 += tr*f_hi(u.x); n2 += tr*f_lo(u.y); n3 += tr*f_hi(u.y);
  }
  float di = 1.0f/den;
  uint2 o; o.x = pack2(n0*di, n1*di); o.y = pack2(n2*di, n3*di);
  *(uint2*)(loc + (size_t)(b*S_ + s)*DM + c0) = o;
}

// ---------------------------------------------------------------------------
// Weight transpose+convert: W [K][1024] fp32 -> WT [1024][K] bf16 (64x64 tiles)
// ---------------------------------------------------------------------------
__global__ __launch_bounds__(256) void k_wcvt(const float* __restrict__ W,
                                              unsigned short* __restrict__ WT, int K){
  __shared__ float Ls[64][68];
  int kt = blockIdx.x >> 4, nt = blockIdx.x & 15;
  int k0 = kt<<6, n0 = nt<<6;
  int tid = threadIdx.x;
#pragma unroll
  for(int p=0; p<4; p++){
    int r = p*16 + (tid>>4), c4 = (tid&15)*4;
    float4 v = *(const float4*)(W + (size_t)(k0+r)*1024 + n0 + c4);
    *(float4*)&Ls[r][c4] = v;
  }
  __syncthreads();
  int nn = tid>>2, kq = tid&3;
#pragma unroll
  for(int c=0; c<4; c++){
    int k = kq*16 + c*4;
    ushort4 u = { f2bf(Ls[k+0][nn]), f2bf(Ls[k+1][nn]), f2bf(Ls[k+2][nn]), f2bf(Ls[k+3][nn]) };
    *(ushort4*)(WT + (size_t)(n0+nn)*K + k0 + k) = u;
  }
}

// ---------------------------------------------------------------------------
// MFMA GEMM 128x128 tile, BK=64, XOR-swizzled LDS, 4 waves x (64x64 quadrant).
// MODE 0: + sigmoid gate mix epilogue -> mixed (bf16).  MODE 1: + bias -> out fp32.
// ---------------------------------------------------------------------------
template<int MODE>
__global__ __launch_bounds__(256) void k_gemm2(const unsigned short* __restrict__ A0,
                                               const unsigned short* __restrict__ A1,
                                               const unsigned short* __restrict__ WT,
                                               const float* __restrict__ bias,
                                               const unsigned short* __restrict__ loc,
                                               const unsigned short* __restrict__ glo,
                                               const unsigned short* __restrict__ bcb,
                                               unsigned short* __restrict__ outb,
                                               float* __restrict__ outf){
  const int KTOT = (MODE==0) ? 2048 : 1024;
  __shared__ __align__(16) unsigned short As[128*64];
  __shared__ __align__(16) unsigned short Bs[128*64];
  const int mt = blockIdx.x >> 3, nt = blockIdx.x & 7;
  const int m0 = mt<<7, n0 = nt<<7;
  const int tid = threadIdx.x, wid = tid>>6, lane = tid&63, quad = lane>>4, tl = lane&15;
  const int mq = (wid&1)*64, nq = (wid>>1)*64;
  f4v acc[4][4];
#pragma unroll
  for(int i=0;i<4;i++)
#pragma unroll
    for(int j=0;j<4;j++) acc[i][j] = (f4v)(0.f);

  for(int kc=0; kc<KTOT; kc+=64){
    __syncthreads();
    const unsigned short* Ab = (MODE==0 && kc>=1024) ? A1 : A0;
    const int kb = (MODE==0) ? (kc & 1023) : kc;
#pragma unroll
    for(int t=0; t<4; t++){
      int cl = tid + t*256, m = cl>>3, c = cl&7;
      uint4 v = *(const uint4*)(Ab + (size_t)(m0+m)*1024 + kb + c*8);
      *(uint4*)&As[m*64 + ((c ^ (m&7))<<3)] = v;
      uint4 w = *(const uint4*)(WT + (size_t)(n0+m)*KTOT + kc + c*8);
      *(uint4*)&Bs[m*64 + ((c ^ (m&7))<<3)] = w;
    }
    __syncthreads();
#pragma unroll
    for(int ks=0; ks<2; ks++){
      s8v af[4], bf[4];
#pragma unroll
      for(int i=0;i<4;i++){
        int ml = mq + i*16 + tl;
        af[i] = *(const s8v*)&As[ml*64 + (((ks*4+quad) ^ (ml&7))<<3)];
      }
#pragma unroll
      for(int j=0;j<4;j++){
        int nl = nq + j*16 + tl;
        bf[j] = *(const s8v*)&Bs[nl*64 + (((ks*4+quad) ^ (nl&7))<<3)];
      }
#pragma unroll
      for(int i=0;i<4;i++)
#pragma unroll
        for(int j=0;j<4;j++)
          acc[i][j] = __builtin_amdgcn_mfma_f32_16x16x32_bf16(af[i], bf[j], acc[i][j], 0, 0, 0);
    }
  }

#pragma unroll
  for(int i=0;i<4;i++){
#pragma unroll
    for(int r=0;r<4;r++){
      int m = m0 + mq + i*16 + quad*4 + r;
      size_t rowb = (size_t)m * 1024;
#pragma unroll
      for(int j=0;j<4;j++){
        int nn = n0 + nq + j*16 + tl;
        float v = acc[i][j][r] + bias[nn];
        if(MODE==0){
          float g  = 1.0f/(1.0f + __expf(-v));
          float lv = f_lo((unsigned int)loc[rowb+nn]);
          float gv = f_lo((unsigned int)glo[rowb+nn]);
          float bv = f_lo((unsigned int)bcb[rowb+nn]);
          outb[rowb+nn] = f2bf(g*lv + (1.0f-g)*gv + bv);
        } else {
          outf[rowb+nn] = v;
        }
      }
    }
  }
}

extern "C" void kernel_launch(void* const* d_in, const int* in_sizes, int n_in,
                              void* d_out, int out_size, void* d_ws, size_t ws_size,
                              hipStream_t stream){
  const float* x  = (const float*)d_in[0];
  const float* gm = (const float*)d_in[1];
  const float* cw = (const float*)d_in[2];
  const float* cb = (const float*)d_in[3];
  const float* mw = (const float*)d_in[4];
  const float* mb = (const float*)d_in[5];
  const float* ow = (const float*)d_in[6];
  const float* ob = (const float*)d_in[7];
  float* out = (float*)d_out;

  char* ws = (char*)d_ws;
  const size_t SZ = (size_t)B_*S_*DM*2;                 // 16.78 MB per bf16 field
  unsigned short* localb = (unsigned short*)(ws);
  unsigned short* globb  = (unsigned short*)(ws + SZ);
  unsigned short* bcb    = (unsigned short*)(ws + 2*SZ);
  unsigned short* kvb    = (unsigned short*)(ws + 3*SZ);
  unsigned short* wso    = (unsigned short*)(ws + 3*SZ + 524288);
  unsigned short* mixed  = wso;                          // first 16.78 MB of wso region
  unsigned short* wt1    = (unsigned short*)(ws + 3*SZ + 524288 + SZ);            // 4 MB
  unsigned short* wt2    = (unsigned short*)(ws + 3*SZ + 524288 + SZ + 4194304);  // 2 MB
  // conv-path scratch overlays localb region (consumed before k_xbf)
  unsigned short* cwb    = (unsigned short*)(ws);               // 8 MB bf16 [1024][4096]
  unsigned short* asta   = (unsigned short*)(ws + 8388608);     // 1 MB bf16 [128][4096]
  float*          cpart  = (float*)        (ws + 9437184);      // 2 MB fp32 [4][128][1024]
  // overlays: xT over globb+bcb (dead until attn<1>/bcxpose); bcT over wso
  float*          xT     = (float*)(ws + SZ);                   // 33.5 MB fp32 [b][1024][4096]
  unsigned short* bcT    = wso;                                 // 16.78 MB bf16 [b][1024][4096]
  unsigned short* xbf    = (unsigned short*)(ws);               // 16.78 MB bf16 x (over conv scratch)

  // conv path (uses ws[0..11.5M])
  k_cvtbf   <<<2048, 256, 0, stream>>>(cw, cwb);
  k_xstage  <<<128,  256, 0, stream>>>(x, asta);
  k_gemmconv<<<dim3(8,4), 256, 0, stream>>>(asta, cwb, cpart);
  k_convred <<<512,  256, 0, stream>>>(cpart, cb, kvb);
  k_gmem    <<<512,  256, 0, stream>>>(gm, kvb);
  // diffusion path (transposed space)
  k_xposef  <<<2048, 256, 0, stream>>>(x, xT);
  k_diffuseT<<<1024, 256, 0, stream>>>(xT, bcT);
  k_bcxpose <<<2048, 256, 0, stream>>>(bcT, bcb);
  // bf16 x for attention (overwrites conv scratch)
  k_cvtbf   <<<4096, 256, 0, stream>>>(x, xbf);
  k_attn<1> <<<dim3(256,2), 256, 0, stream>>>(xbf, kvb, globb);
  k_attn<0> <<<dim3(480,2), 256, 0, stream>>>(xbf, kvb, wso);   // overwrites bcT (dead)
  k_combine <<<8192, 256, 0, stream>>>(wso, localb);            // overwrites xbf (dead)
  k_wcvt    <<<512,  256, 0, stream>>>(mw, wt1, 2048);
  k_wcvt    <<<256,  256, 0, stream>>>(ow, wt2, 1024);
  k_gemm2<0><<<512, 256, 0, stream>>>(localb, globb, wt1, mb, localb, globb, bcb, mixed, nullptr);
  k_gemm2<1><<<512, 256, 0, stream>>>(mixed, nullptr, wt2, ob, nullptr, nullptr, nullptr, nullptr, out);
}